// Round 8
// baseline (713.783 us; speedup 1.0000x reference)
//
#include <hip/hip_runtime.h>

#define N_NODES 100000
#define N_EDGES 3200000
#define F_IN    128
#define H_DIM   32
#define B_GR    256
#define NEG     0.2f

#define FBIN_SZ  200
#define N_FBIN   (N_NODES / FBIN_SZ)        // 500
#define BIN_CAP  8192                        // mean 6400, +22 sigma
#define PART_T   1024
#define PART_E   (PART_T * 4)                // 4096 edges per block
#define PART_NBLK ((N_EDGES / 4 + PART_T - 1) / PART_T)  // 782

#define LIN_NODES 16

// ---- monotonic float<->uint encoding for atomicMax on floats ----
__device__ __forceinline__ unsigned fenc(float f) {
    unsigned u = __float_as_uint(f);
    return (u & 0x80000000u) ? ~u : (u | 0x80000000u);
}
__device__ __forceinline__ float fdec(unsigned u) {
    return (u & 0x80000000u) ? __uint_as_float(u & 0x7FFFFFFFu)
                             : __uint_as_float(~u);
}

// K1: xl = x@Wl, xr = x@Wr. 16 nodes/block, 2 nodes/thread, float4 LDS reads.
__global__ __launch_bounds__(256) void k_linear(
    const float* __restrict__ x, const float* __restrict__ Wl,
    const float* __restrict__ Wr, float* __restrict__ xl, float* __restrict__ xr)
{
    __shared__ float Wls[F_IN * H_DIM];
    __shared__ float Wrs[F_IN * H_DIM];
    __shared__ float xs[LIN_NODES * F_IN];
    int t = threadIdx.x;
    for (int i = t; i < F_IN * H_DIM; i += 256) { Wls[i] = Wl[i]; Wrs[i] = Wr[i]; }
    size_t base = (size_t)blockIdx.x * LIN_NODES;
    const float4* xg = (const float4*)(x + base * F_IN);
    float4* xs4 = (float4*)xs;
    xs4[t] = xg[t];
    xs4[t + 256] = xg[t + 256];
    __syncthreads();
    int nl = t >> 5, h = t & 31;
    float al0 = 0.f, ar0 = 0.f, al1 = 0.f, ar1 = 0.f;
    const float4* xa4 = (const float4*)(xs + nl * F_IN);
    const float4* xb4 = (const float4*)(xs + (nl + 8) * F_IN);
    #pragma unroll 8
    for (int f4 = 0; f4 < 32; ++f4) {
        float4 xa = xa4[f4], xb = xb4[f4];
        int fb = f4 * 4;
        float w;
        w = Wls[(fb + 0) * 32 + h]; al0 = fmaf(xa.x, w, al0); al1 = fmaf(xb.x, w, al1);
        w = Wls[(fb + 1) * 32 + h]; al0 = fmaf(xa.y, w, al0); al1 = fmaf(xb.y, w, al1);
        w = Wls[(fb + 2) * 32 + h]; al0 = fmaf(xa.z, w, al0); al1 = fmaf(xb.z, w, al1);
        w = Wls[(fb + 3) * 32 + h]; al0 = fmaf(xa.w, w, al0); al1 = fmaf(xb.w, w, al1);
        w = Wrs[(fb + 0) * 32 + h]; ar0 = fmaf(xa.x, w, ar0); ar1 = fmaf(xb.x, w, ar1);
        w = Wrs[(fb + 1) * 32 + h]; ar0 = fmaf(xa.y, w, ar0); ar1 = fmaf(xb.y, w, ar1);
        w = Wrs[(fb + 2) * 32 + h]; ar0 = fmaf(xa.z, w, ar0); ar1 = fmaf(xb.z, w, ar1);
        w = Wrs[(fb + 3) * 32 + h]; ar0 = fmaf(xa.w, w, ar0); ar1 = fmaf(xb.w, w, ar1);
    }
    size_t n0 = base + nl, n1 = base + nl + 8;
    xl[n0 * 32 + h] = al0; xr[n0 * 32 + h] = ar0;
    xl[n1 * 32 + h] = al1; xr[n1 * 32 + h] = ar1;
}

// K2: one-pass edge binning into 500 fine bins (200 dst nodes each).
// Block-local LDS counting sort; ~500 block-aggregated global atomics per
// block; staged flush gives ~32B-coalesced runs per bin.
// Packed u32: (dst_local << 17) | src   (src < 2^17, dst_local < 2^8).
__global__ __launch_bounds__(1024) void k_part(
    const int* __restrict__ ei, int* __restrict__ bcnt, unsigned* __restrict__ binbuf)
{
    __shared__ int lcnt[512];
    __shared__ int sc[512];
    __shared__ int lbase[512];
    __shared__ unsigned staged[PART_E];
    __shared__ unsigned short sbin[PART_E];
    int t = threadIdx.x;
    if (t < 512) lcnt[t] = 0;
    __syncthreads();
    int i = blockIdx.x * PART_T + t;
    bool valid = i < N_EDGES / 4;
    int4 s4, d4;
    int b0 = 0, b1 = 0, b2 = 0, b3 = 0, o0 = 0, o1 = 0, o2 = 0, o3 = 0;
    if (valid) {
        s4 = ((const int4*)ei)[i];
        d4 = ((const int4*)(ei + N_EDGES))[i];
        b0 = d4.x / FBIN_SZ; b1 = d4.y / FBIN_SZ;
        b2 = d4.z / FBIN_SZ; b3 = d4.w / FBIN_SZ;
        o0 = atomicAdd(&lcnt[b0], 1);
        o1 = atomicAdd(&lcnt[b1], 1);
        o2 = atomicAdd(&lcnt[b2], 1);
        o3 = atomicAdd(&lcnt[b3], 1);
    }
    __syncthreads();
    if (t < 512) sc[t] = lcnt[t];
    __syncthreads();
    for (int off = 1; off < 512; off <<= 1) {      // inclusive scan (Hillis-Steele)
        int v = 0;
        if (t < 512 && t >= off) v = sc[t - off];
        __syncthreads();
        if (t < 512) sc[t] += v;
        __syncthreads();
    }
    if (t < N_FBIN && lcnt[t] > 0) lbase[t] = atomicAdd(&bcnt[t], lcnt[t]);
    if (valid) {
        int p;
        p = sc[b0] - lcnt[b0] + o0;
        staged[p] = ((unsigned)(d4.x - b0 * FBIN_SZ) << 17) | (unsigned)s4.x; sbin[p] = (unsigned short)b0;
        p = sc[b1] - lcnt[b1] + o1;
        staged[p] = ((unsigned)(d4.y - b1 * FBIN_SZ) << 17) | (unsigned)s4.y; sbin[p] = (unsigned short)b1;
        p = sc[b2] - lcnt[b2] + o2;
        staged[p] = ((unsigned)(d4.z - b2 * FBIN_SZ) << 17) | (unsigned)s4.z; sbin[p] = (unsigned short)b2;
        p = sc[b3] - lcnt[b3] + o3;
        staged[p] = ((unsigned)(d4.w - b3 * FBIN_SZ) << 17) | (unsigned)s4.w; sbin[p] = (unsigned short)b3;
    }
    __syncthreads();
    int total = sc[511];
    for (int k = t; k < total; k += PART_T) {
        int b = sbin[k];
        binbuf[(size_t)b * BIN_CAP + lbase[b] + (k - (sc[b] - lcnt[b]))] = staged[k];
    }
}

// K3: fused score + softmax (no max pass) + aggregate + bias + graph max-pool.
// Block = one fine bin (200 dst nodes). acc[200][32|z] in LDS, stride 33
// (bank = dloc+h mod 32, random dloc -> ~2-way, free). Per edge: gather
// xl[src] row to regs, xr[dst] from L2-hot window, in-thread 32-dim dot,
// exp, 33 LDS float atomics. Self-loop = non-atomic init pass.
__global__ __launch_bounds__(512) void k_aggregate(
    const unsigned* __restrict__ binbuf, const int* __restrict__ bcnt,
    const float* __restrict__ xl, const float* __restrict__ xr,
    const float* __restrict__ att, const float* __restrict__ bias,
    const int* __restrict__ batch, unsigned* __restrict__ gu)
{
    __shared__ float accz[FBIN_SZ * 33];   // 26.4 KB: [dloc][h0..31 | z]
    __shared__ float lds_att[H_DIM];
    __shared__ float lds_bias[H_DIM];
    __shared__ unsigned lmax[64];          // bin spans <= 2 graphs (200 < 390)
    __shared__ int lg0;
    int t = threadIdx.x;
    int bin = blockIdx.x;

    if (t < H_DIM) { lds_att[t] = att[t]; lds_bias[t] = bias[t]; }
    if (t < 64) lmax[t] = 0u;              // fenc(-inf)
    if (t == 0) lg0 = batch[bin * FBIN_SZ];

    if (t < FBIN_SZ) {                     // self-loop init (non-atomic stores)
        int n = bin * FBIN_SZ + t;
        const float4* xlp = (const float4*)(xl + (size_t)n * H_DIM);
        const float4* xrp = (const float4*)(xr + (size_t)n * H_DIM);
        const float4* av4 = (const float4*)att;
        float4 R[8]; float pr = 0.f;
        #pragma unroll
        for (int c = 0; c < 8; ++c) {
            R[c] = xlp[c]; float4 xv = xrp[c]; float4 av = av4[c];
            float vx = R[c].x + xv.x; vx = fmaxf(vx, vx * NEG); pr = fmaf(vx, av.x, pr);
            float vy = R[c].y + xv.y; vy = fmaxf(vy, vy * NEG); pr = fmaf(vy, av.y, pr);
            float vz = R[c].z + xv.z; vz = fmaxf(vz, vz * NEG); pr = fmaf(vz, av.z, pr);
            float vw = R[c].w + xv.w; vw = fmaxf(vw, vw * NEG); pr = fmaf(vw, av.w, pr);
        }
        float p = __expf(fminf(pr, 70.f));
        float* arow = &accz[t * 33];
        #pragma unroll
        for (int c = 0; c < 8; ++c) {
            arow[4 * c + 0] = p * R[c].x;
            arow[4 * c + 1] = p * R[c].y;
            arow[4 * c + 2] = p * R[c].z;
            arow[4 * c + 3] = p * R[c].w;
        }
        arow[32] = p;
    }
    __syncthreads();

    int n_e = bcnt[bin];
    const unsigned* bb = binbuf + (size_t)bin * BIN_CAP;
    for (int i = t; i < n_e; i += 512) {
        unsigned u = bb[i];
        int dloc = (int)(u >> 17);
        int s    = (int)(u & 0x1FFFFu);
        const float4* xlp = (const float4*)(xl + (size_t)s * H_DIM);
        const float4* xrp = (const float4*)(xr + (size_t)(bin * FBIN_SZ + dloc) * H_DIM);
        const float4* av4 = (const float4*)lds_att;
        float4 R[8]; float pr = 0.f;
        #pragma unroll
        for (int c = 0; c < 8; ++c) {
            R[c] = xlp[c]; float4 xv = xrp[c]; float4 av = av4[c];
            float vx = R[c].x + xv.x; vx = fmaxf(vx, vx * NEG); pr = fmaf(vx, av.x, pr);
            float vy = R[c].y + xv.y; vy = fmaxf(vy, vy * NEG); pr = fmaf(vy, av.y, pr);
            float vz = R[c].z + xv.z; vz = fmaxf(vz, vz * NEG); pr = fmaf(vz, av.z, pr);
            float vw = R[c].w + xv.w; vw = fmaxf(vw, vw * NEG); pr = fmaf(vw, av.w, pr);
        }
        float p = __expf(fminf(pr, 70.f));
        float* arow = &accz[dloc * 33];
        #pragma unroll
        for (int c = 0; c < 8; ++c) {
            atomicAdd(&arow[4 * c + 0], p * R[c].x);
            atomicAdd(&arow[4 * c + 1], p * R[c].y);
            atomicAdd(&arow[4 * c + 2], p * R[c].z);
            atomicAdd(&arow[4 * c + 3], p * R[c].w);
        }
        atomicAdd(&arow[32], p);
    }
    __syncthreads();

    if (t < FBIN_SZ) {                     // normalize + bias + LDS pre-max
        int n = bin * FBIN_SZ + t;
        int gi = batch[n] - lg0;           // 0 or 1
        float inv = 1.f / accz[t * 33 + 32];
        #pragma unroll
        for (int h = 0; h < H_DIM; ++h) {
            float outv = accz[t * 33 + h] * inv + lds_bias[h];
            atomicMax(&lmax[gi * 32 + h], fenc(outv));
        }
    }
    __syncthreads();
    if (t < 64) {                          // flush <=2 graphs to global
        int g = lg0 + (t >> 5);
        int glast = batch[bin * FBIN_SZ + FBIN_SZ - 1];
        if (g <= glast) atomicMax(&gu[g * H_DIM + (t & 31)], lmax[t]);
    }
}

// K4: h1 = relu(g @ W1 + b1)
__global__ __launch_bounds__(256) void k_mlp1(
    const unsigned* __restrict__ gu, const float* __restrict__ W1,
    const float* __restrict__ b1, float* __restrict__ h1)
{
    __shared__ float gs[H_DIM];
    int b = blockIdx.x, t = threadIdx.x;
    if (t < H_DIM) gs[t] = fdec(gu[b * H_DIM + t]);
    __syncthreads();
    for (int jj = 0; jj < 4; ++jj) {
        int j = jj * 256 + t;
        float a = b1[j];
        #pragma unroll
        for (int k = 0; k < H_DIM; ++k) a = fmaf(gs[k], W1[k * 1024 + j], a);
        h1[(size_t)b * 1024 + j] = fmaxf(a, 0.f);
    }
}

// K5: h2 = relu(h1 @ W2 + b2), 4 graphs per block
__global__ __launch_bounds__(512) void k_mlp2(
    const float* __restrict__ h1, const float* __restrict__ W2,
    const float* __restrict__ b2, float* __restrict__ h2)
{
    __shared__ float hs[4][1024];
    int b0 = blockIdx.x * 4, t = threadIdx.x;
    for (int r = 0; r < 4; ++r)
        for (int k = t; k < 1024; k += 512) hs[r][k] = h1[(size_t)(b0 + r) * 1024 + k];
    __syncthreads();
    float bb = b2[t];
    float a0 = bb, a1 = bb, a2 = bb, a3 = bb;
    for (int k = 0; k < 1024; ++k) {
        float w = W2[(size_t)k * 512 + t];
        a0 = fmaf(hs[0][k], w, a0);
        a1 = fmaf(hs[1][k], w, a1);
        a2 = fmaf(hs[2][k], w, a2);
        a3 = fmaf(hs[3][k], w, a3);
    }
    h2[(size_t)(b0 + 0) * 512 + t] = fmaxf(a0, 0.f);
    h2[(size_t)(b0 + 1) * 512 + t] = fmaxf(a1, 0.f);
    h2[(size_t)(b0 + 2) * 512 + t] = fmaxf(a2, 0.f);
    h2[(size_t)(b0 + 3) * 512 + t] = fmaxf(a3, 0.f);
}

// K6: out = h2 @ W3 + b3
__global__ __launch_bounds__(256) void k_mlp3(
    const float* __restrict__ h2, const float* __restrict__ W3,
    const float* __restrict__ b3, float* __restrict__ out)
{
    int b = blockIdx.x, t = threadIdx.x;
    int c = t >> 6, lane = t & 63;
    float a = 0.f;
    for (int k = lane; k < 512; k += 64)
        a = fmaf(h2[(size_t)b * 512 + k], W3[k * 4 + c], a);
    for (int off = 32; off; off >>= 1) a += __shfl_down(a, off);
    if (lane == 0) out[b * 4 + c] = a + b3[c];
}

extern "C" void kernel_launch(void* const* d_in, const int* in_sizes, int n_in,
                              void* d_out, int out_size, void* d_ws, size_t ws_size,
                              hipStream_t stream)
{
    const float* x     = (const float*)d_in[0];
    const int*   ei    = (const int*)d_in[1];
    const int*   batch = (const int*)d_in[2];
    const float* Wl    = (const float*)d_in[3];
    const float* Wr    = (const float*)d_in[4];
    const float* att   = (const float*)d_in[5];
    const float* bias  = (const float*)d_in[6];
    const float* W1    = (const float*)d_in[7];
    const float* b1    = (const float*)d_in[8];
    const float* W2    = (const float*)d_in[9];
    const float* b2    = (const float*)d_in[10];
    const float* W3    = (const float*)d_in[11];
    const float* b3    = (const float*)d_in[12];
    float* out = (float*)d_out;

    // workspace layout (~44 MB)
    float*    xl     = (float*)d_ws;                               // 3.2M f
    float*    xr     = xl + (size_t)N_NODES * H_DIM;               // 3.2M f
    unsigned* binbuf = (unsigned*)(xr + (size_t)N_NODES * H_DIM);  // 500*8192 + slack
    int*      bcnt   = (int*)(binbuf + (size_t)N_FBIN * BIN_CAP + 16384); // 512 [memset]
    unsigned* gu     = (unsigned*)(bcnt + 512);                    // 8192 [memset]
    float*    h1     = (float*)(gu + B_GR * H_DIM);                // 262144
    float*    h2     = h1 + (size_t)B_GR * 1024;                   // 131072

    hipMemsetAsync(bcnt, 0, (size_t)(512 + B_GR * H_DIM) * sizeof(int), stream);

    k_part  <<<PART_NBLK, PART_T, 0, stream>>>(ei, bcnt, binbuf);
    k_linear<<<N_NODES / LIN_NODES, 256, 0, stream>>>(x, Wl, Wr, xl, xr);
    k_aggregate<<<N_FBIN, 512, 0, stream>>>(binbuf, bcnt, xl, xr, att, bias, batch, gu);
    k_mlp1<<<B_GR, 256, 0, stream>>>(gu, W1, b1, h1);
    k_mlp2<<<B_GR / 4, 512, 0, stream>>>(h1, W2, b2, h2);
    k_mlp3<<<B_GR, 256, 0, stream>>>(h2, W3, b3, out);
}

// Round 9
// 311.591 us; speedup vs baseline: 2.2908x; 2.2908x over previous
//
#include <hip/hip_runtime.h>

#define N_NODES 100000
#define N_EDGES 3200000
#define F_IN    128
#define H_DIM   32
#define B_GR    256
#define NEG     0.2f

#define FBIN_SZ  200
#define N_FBIN   (N_NODES / FBIN_SZ)        // 500
#define BIN_CAP  8192                        // mean 6400, +22 sigma
#define PART_T   1024
#define PART_E   (PART_T * 4)                // 4096 edges per block
#define PART_NBLK ((N_EDGES / 4 + PART_T - 1) / PART_T)  // 782

#define LIN_NODES 16

// ---- monotonic float<->uint encoding for atomicMax on floats ----
__device__ __forceinline__ unsigned fenc(float f) {
    unsigned u = __float_as_uint(f);
    return (u & 0x80000000u) ? ~u : (u | 0x80000000u);
}
__device__ __forceinline__ float fdec(unsigned u) {
    return (u & 0x80000000u) ? __uint_as_float(u & 0x7FFFFFFFu)
                             : __uint_as_float(~u);
}

// K1: xl = x@Wl, xr = x@Wr. 16 nodes/block, 2 nodes/thread, float4 LDS reads.
__global__ __launch_bounds__(256) void k_linear(
    const float* __restrict__ x, const float* __restrict__ Wl,
    const float* __restrict__ Wr, float* __restrict__ xl, float* __restrict__ xr)
{
    __shared__ float Wls[F_IN * H_DIM];
    __shared__ float Wrs[F_IN * H_DIM];
    __shared__ float xs[LIN_NODES * F_IN];
    int t = threadIdx.x;
    for (int i = t; i < F_IN * H_DIM; i += 256) { Wls[i] = Wl[i]; Wrs[i] = Wr[i]; }
    size_t base = (size_t)blockIdx.x * LIN_NODES;
    const float4* xg = (const float4*)(x + base * F_IN);
    float4* xs4 = (float4*)xs;
    xs4[t] = xg[t];
    xs4[t + 256] = xg[t + 256];
    __syncthreads();
    int nl = t >> 5, h = t & 31;
    float al0 = 0.f, ar0 = 0.f, al1 = 0.f, ar1 = 0.f;
    const float4* xa4 = (const float4*)(xs + nl * F_IN);
    const float4* xb4 = (const float4*)(xs + (nl + 8) * F_IN);
    #pragma unroll 8
    for (int f4 = 0; f4 < 32; ++f4) {
        float4 xa = xa4[f4], xb = xb4[f4];
        int fb = f4 * 4;
        float w;
        w = Wls[(fb + 0) * 32 + h]; al0 = fmaf(xa.x, w, al0); al1 = fmaf(xb.x, w, al1);
        w = Wls[(fb + 1) * 32 + h]; al0 = fmaf(xa.y, w, al0); al1 = fmaf(xb.y, w, al1);
        w = Wls[(fb + 2) * 32 + h]; al0 = fmaf(xa.z, w, al0); al1 = fmaf(xb.z, w, al1);
        w = Wls[(fb + 3) * 32 + h]; al0 = fmaf(xa.w, w, al0); al1 = fmaf(xb.w, w, al1);
        w = Wrs[(fb + 0) * 32 + h]; ar0 = fmaf(xa.x, w, ar0); ar1 = fmaf(xb.x, w, ar1);
        w = Wrs[(fb + 1) * 32 + h]; ar0 = fmaf(xa.y, w, ar0); ar1 = fmaf(xb.y, w, ar1);
        w = Wrs[(fb + 2) * 32 + h]; ar0 = fmaf(xa.z, w, ar0); ar1 = fmaf(xb.z, w, ar1);
        w = Wrs[(fb + 3) * 32 + h]; ar0 = fmaf(xa.w, w, ar0); ar1 = fmaf(xb.w, w, ar1);
    }
    size_t n0 = base + nl, n1 = base + nl + 8;
    xl[n0 * 32 + h] = al0; xr[n0 * 32 + h] = ar0;
    xl[n1 * 32 + h] = al1; xr[n1 * 32 + h] = ar1;
}

// K2: one-pass edge binning into 500 fine bins (200 dst nodes each).
// Block-local LDS counting sort; ~500 block-aggregated global atomics per
// block; staged flush gives coalesced runs per bin.
// Packed u32: (dst_local << 17) | src   (src < 2^17, dst_local < 2^8).
__global__ __launch_bounds__(1024) void k_part(
    const int* __restrict__ ei, int* __restrict__ bcnt, unsigned* __restrict__ binbuf)
{
    __shared__ int lcnt[512];
    __shared__ int sc[512];
    __shared__ int lbase[512];
    __shared__ unsigned staged[PART_E];
    __shared__ unsigned short sbin[PART_E];
    int t = threadIdx.x;
    if (t < 512) lcnt[t] = 0;
    __syncthreads();
    int i = blockIdx.x * PART_T + t;
    bool valid = i < N_EDGES / 4;
    int4 s4, d4;
    int b0 = 0, b1 = 0, b2 = 0, b3 = 0, o0 = 0, o1 = 0, o2 = 0, o3 = 0;
    if (valid) {
        s4 = ((const int4*)ei)[i];
        d4 = ((const int4*)(ei + N_EDGES))[i];
        b0 = d4.x / FBIN_SZ; b1 = d4.y / FBIN_SZ;
        b2 = d4.z / FBIN_SZ; b3 = d4.w / FBIN_SZ;
        o0 = atomicAdd(&lcnt[b0], 1);
        o1 = atomicAdd(&lcnt[b1], 1);
        o2 = atomicAdd(&lcnt[b2], 1);
        o3 = atomicAdd(&lcnt[b3], 1);
    }
    __syncthreads();
    if (t < 512) sc[t] = lcnt[t];
    __syncthreads();
    for (int off = 1; off < 512; off <<= 1) {      // inclusive scan (Hillis-Steele)
        int v = 0;
        if (t < 512 && t >= off) v = sc[t - off];
        __syncthreads();
        if (t < 512) sc[t] += v;
        __syncthreads();
    }
    if (t < N_FBIN && lcnt[t] > 0) lbase[t] = atomicAdd(&bcnt[t], lcnt[t]);
    if (valid) {
        int p;
        p = sc[b0] - lcnt[b0] + o0;
        staged[p] = ((unsigned)(d4.x - b0 * FBIN_SZ) << 17) | (unsigned)s4.x; sbin[p] = (unsigned short)b0;
        p = sc[b1] - lcnt[b1] + o1;
        staged[p] = ((unsigned)(d4.y - b1 * FBIN_SZ) << 17) | (unsigned)s4.y; sbin[p] = (unsigned short)b1;
        p = sc[b2] - lcnt[b2] + o2;
        staged[p] = ((unsigned)(d4.z - b2 * FBIN_SZ) << 17) | (unsigned)s4.z; sbin[p] = (unsigned short)b2;
        p = sc[b3] - lcnt[b3] + o3;
        staged[p] = ((unsigned)(d4.w - b3 * FBIN_SZ) << 17) | (unsigned)s4.w; sbin[p] = (unsigned short)b3;
    }
    __syncthreads();
    int total = sc[511];
    for (int k = t; k < total; k += PART_T) {
        int b = sbin[k];
        binbuf[(size_t)b * BIN_CAP + lbase[b] + (k - (sc[b] - lcnt[b]))] = staged[k];
    }
}

// K3: per-bin in-LDS CSR build + fused score/softmax/aggregate/pool.
// Block = one bin (200 dst nodes, <=8192 edges). Phase 1: LDS counting sort
// of the bin's edges by dst_local (int LDS atomics, 2/edge). Phase 2:
// half-wave = node, lane = h: coalesced 128B xl[src] gathers, in-half
// shfl-reduce score, exp (no max pass; validated r5-r8), 2-edge unroll.
__global__ __launch_bounds__(512) void k_aggregate(
    const unsigned* __restrict__ binbuf, const int* __restrict__ bcnt,
    const float* __restrict__ xl, const float* __restrict__ xr,
    const float* __restrict__ att, const float* __restrict__ bias,
    const int* __restrict__ batch, unsigned* __restrict__ gu)
{
    __shared__ unsigned eL[BIN_CAP];      // 32 KB sorted edge list
    __shared__ int cnt[256];
    __shared__ int sc[256];
    __shared__ int cur[256];
    __shared__ unsigned lmax[64];         // bin spans <= 2 graphs (200 < 390)
    int t = threadIdx.x;
    int bin = blockIdx.x;
    int n_e = bcnt[bin];
    const unsigned* bb = binbuf + (size_t)bin * BIN_CAP;

    if (t < 256) cnt[t] = 0;
    if (t < 64) lmax[t] = 0u;             // encodes -inf
    __syncthreads();
    for (int i = t; i < n_e; i += 512)
        atomicAdd(&cnt[bb[i] >> 17], 1);
    __syncthreads();
    if (t < 256) sc[t] = cnt[t];
    __syncthreads();
    for (int off = 1; off < 256; off <<= 1) {   // inclusive scan over 256
        int v = 0;
        if (t < 256 && t >= off) v = sc[t - off];
        __syncthreads();
        if (t < 256) sc[t] += v;
        __syncthreads();
    }
    if (t < 256) cur[t] = sc[t] - cnt[t];
    __syncthreads();
    for (int i = t; i < n_e; i += 512) {
        unsigned u = bb[i];
        int p = atomicAdd(&cur[u >> 17], 1);
        eL[p] = u;
    }
    __syncthreads();

    int lane = t & 31;                    // h
    int hw = t >> 5;                      // half-wave 0..15
    float a = att[lane], bi = bias[lane];
    int lg0 = batch[bin * FBIN_SZ];

    for (int nl = hw; nl < FBIN_SZ; nl += 16) {
        int n = bin * FBIN_SZ + nl;
        int e0 = (nl > 0) ? sc[nl - 1] : 0;
        int e1 = sc[nl];
        float xrv = xr[(size_t)n * H_DIM + lane];
        float xlv = xl[(size_t)n * H_DIM + lane];
        // self-loop
        float v = xlv + xrv; v = fmaxf(v, v * NEG);
        float tt = v * a;
        tt += __shfl_xor(tt, 16); tt += __shfl_xor(tt, 8);
        tt += __shfl_xor(tt, 4);  tt += __shfl_xor(tt, 2); tt += __shfl_xor(tt, 1);
        float p0 = __expf(fminf(tt, 70.f));
        float z0 = p0, z1 = 0.f, ac0 = p0 * xlv, ac1 = 0.f;
        int j = e0;
        for (; j + 1 < e1; j += 2) {
            int sA = (int)(eL[j] & 0x1FFFFu);
            int sB = (int)(eL[j + 1] & 0x1FFFFu);
            float xsA = xl[(size_t)sA * H_DIM + lane];
            float xsB = xl[(size_t)sB * H_DIM + lane];
            float vA = xsA + xrv; vA = fmaxf(vA, vA * NEG);
            float vB = xsB + xrv; vB = fmaxf(vB, vB * NEG);
            float tA = vA * a, tB = vB * a;
            tA += __shfl_xor(tA, 16); tB += __shfl_xor(tB, 16);
            tA += __shfl_xor(tA, 8);  tB += __shfl_xor(tB, 8);
            tA += __shfl_xor(tA, 4);  tB += __shfl_xor(tB, 4);
            tA += __shfl_xor(tA, 2);  tB += __shfl_xor(tB, 2);
            tA += __shfl_xor(tA, 1);  tB += __shfl_xor(tB, 1);
            float pA = __expf(fminf(tA, 70.f));
            float pB = __expf(fminf(tB, 70.f));
            z0 += pA; z1 += pB;
            ac0 = fmaf(pA, xsA, ac0);
            ac1 = fmaf(pB, xsB, ac1);
        }
        if (j < e1) {
            int s = (int)(eL[j] & 0x1FFFFu);
            float xs = xl[(size_t)s * H_DIM + lane];
            float v2 = xs + xrv; v2 = fmaxf(v2, v2 * NEG);
            float t2 = v2 * a;
            t2 += __shfl_xor(t2, 16); t2 += __shfl_xor(t2, 8);
            t2 += __shfl_xor(t2, 4);  t2 += __shfl_xor(t2, 2); t2 += __shfl_xor(t2, 1);
            float p = __expf(fminf(t2, 70.f));
            z0 += p; ac0 = fmaf(p, xs, ac0);
        }
        float outv = (ac0 + ac1) / (z0 + z1) + bi;
        int gi = batch[n] - lg0;          // 0 or 1
        atomicMax(&lmax[gi * 32 + lane], fenc(outv));
    }
    __syncthreads();
    if (t < 64) {                         // flush <=2 graphs to global
        int g = lg0 + (t >> 5);
        int glast = batch[bin * FBIN_SZ + FBIN_SZ - 1];
        if (g <= glast) atomicMax(&gu[g * H_DIM + (t & 31)], lmax[t]);
    }
}

// K4: h1 = relu(g @ W1 + b1)
__global__ __launch_bounds__(256) void k_mlp1(
    const unsigned* __restrict__ gu, const float* __restrict__ W1,
    const float* __restrict__ b1, float* __restrict__ h1)
{
    __shared__ float gs[H_DIM];
    int b = blockIdx.x, t = threadIdx.x;
    if (t < H_DIM) gs[t] = fdec(gu[b * H_DIM + t]);
    __syncthreads();
    for (int jj = 0; jj < 4; ++jj) {
        int j = jj * 256 + t;
        float a = b1[j];
        #pragma unroll
        for (int k = 0; k < H_DIM; ++k) a = fmaf(gs[k], W1[k * 1024 + j], a);
        h1[(size_t)b * 1024 + j] = fmaxf(a, 0.f);
    }
}

// K5: h2 = relu(h1 @ W2 + b2), 4 graphs per block
__global__ __launch_bounds__(512) void k_mlp2(
    const float* __restrict__ h1, const float* __restrict__ W2,
    const float* __restrict__ b2, float* __restrict__ h2)
{
    __shared__ float hs[4][1024];
    int b0 = blockIdx.x * 4, t = threadIdx.x;
    for (int r = 0; r < 4; ++r)
        for (int k = t; k < 1024; k += 512) hs[r][k] = h1[(size_t)(b0 + r) * 1024 + k];
    __syncthreads();
    float bb = b2[t];
    float a0 = bb, a1 = bb, a2 = bb, a3 = bb;
    for (int k = 0; k < 1024; ++k) {
        float w = W2[(size_t)k * 512 + t];
        a0 = fmaf(hs[0][k], w, a0);
        a1 = fmaf(hs[1][k], w, a1);
        a2 = fmaf(hs[2][k], w, a2);
        a3 = fmaf(hs[3][k], w, a3);
    }
    h2[(size_t)(b0 + 0) * 512 + t] = fmaxf(a0, 0.f);
    h2[(size_t)(b0 + 1) * 512 + t] = fmaxf(a1, 0.f);
    h2[(size_t)(b0 + 2) * 512 + t] = fmaxf(a2, 0.f);
    h2[(size_t)(b0 + 3) * 512 + t] = fmaxf(a3, 0.f);
}

// K6: out = h2 @ W3 + b3
__global__ __launch_bounds__(256) void k_mlp3(
    const float* __restrict__ h2, const float* __restrict__ W3,
    const float* __restrict__ b3, float* __restrict__ out)
{
    int b = blockIdx.x, t = threadIdx.x;
    int c = t >> 6, lane = t & 63;
    float a = 0.f;
    for (int k = lane; k < 512; k += 64)
        a = fmaf(h2[(size_t)b * 512 + k], W3[k * 4 + c], a);
    for (int off = 32; off; off >>= 1) a += __shfl_down(a, off);
    if (lane == 0) out[b * 4 + c] = a + b3[c];
}

extern "C" void kernel_launch(void* const* d_in, const int* in_sizes, int n_in,
                              void* d_out, int out_size, void* d_ws, size_t ws_size,
                              hipStream_t stream)
{
    const float* x     = (const float*)d_in[0];
    const int*   ei    = (const int*)d_in[1];
    const int*   batch = (const int*)d_in[2];
    const float* Wl    = (const float*)d_in[3];
    const float* Wr    = (const float*)d_in[4];
    const float* att   = (const float*)d_in[5];
    const float* bias  = (const float*)d_in[6];
    const float* W1    = (const float*)d_in[7];
    const float* b1    = (const float*)d_in[8];
    const float* W2    = (const float*)d_in[9];
    const float* b2    = (const float*)d_in[10];
    const float* W3    = (const float*)d_in[11];
    const float* b3    = (const float*)d_in[12];
    float* out = (float*)d_out;

    // workspace layout (~44 MB)
    float*    xl     = (float*)d_ws;                               // 3.2M f
    float*    xr     = xl + (size_t)N_NODES * H_DIM;               // 3.2M f
    unsigned* binbuf = (unsigned*)(xr + (size_t)N_NODES * H_DIM);  // 500*8192
    int*      bcnt   = (int*)(binbuf + (size_t)N_FBIN * BIN_CAP + 16384); // 512 [memset]
    unsigned* gu     = (unsigned*)(bcnt + 512);                    // 8192 [memset]
    float*    h1     = (float*)(gu + B_GR * H_DIM);                // 262144
    float*    h2     = h1 + (size_t)B_GR * 1024;                   // 131072

    hipMemsetAsync(bcnt, 0, (size_t)(512 + B_GR * H_DIM) * sizeof(int), stream);

    k_part  <<<PART_NBLK, PART_T, 0, stream>>>(ei, bcnt, binbuf);
    k_linear<<<N_NODES / LIN_NODES, 256, 0, stream>>>(x, Wl, Wr, xl, xr);
    k_aggregate<<<N_FBIN, 512, 0, stream>>>(binbuf, bcnt, xl, xr, att, bias, batch, gu);
    k_mlp1<<<B_GR, 256, 0, stream>>>(gu, W1, b1, h1);
    k_mlp2<<<B_GR / 4, 512, 0, stream>>>(h1, W2, b2, h2);
    k_mlp3<<<B_GR, 256, 0, stream>>>(h2, W3, b3, out);
}

// Round 10
// 234.151 us; speedup vs baseline: 3.0484x; 1.3307x over previous
//
#include <hip/hip_runtime.h>

#define N_NODES 100000
#define N_EDGES 3200000
#define F_IN    128
#define H_DIM   32
#define B_GR    256
#define NEG     0.2f

#define FBIN_SZ  100
#define N_FBIN   (N_NODES / FBIN_SZ)        // 1000
#define BIN_CAP  4096                        // mean 3200, +15.8 sigma
#define CPAD     16                          // bcnt 64B padding
#define PART_T   1024
#define PART_E   (PART_T * 4)                // 4096 edges per block
#define PART_NBLK ((N_EDGES / 4 + PART_T - 1) / PART_T)  // 782

#define LIN_NODES 16

// ---- monotonic float<->uint encoding for atomicMax on floats ----
__device__ __forceinline__ unsigned fenc(float f) {
    unsigned u = __float_as_uint(f);
    return (u & 0x80000000u) ? ~u : (u | 0x80000000u);
}
__device__ __forceinline__ float fdec(unsigned u) {
    return (u & 0x80000000u) ? __uint_as_float(u & 0x7FFFFFFFu)
                             : __uint_as_float(~u);
}

// K1: xl = x@Wl, xr = x@Wr. 16 nodes/block, 2 nodes/thread, float4 LDS reads.
__global__ __launch_bounds__(256) void k_linear(
    const float* __restrict__ x, const float* __restrict__ Wl,
    const float* __restrict__ Wr, float* __restrict__ xl, float* __restrict__ xr)
{
    __shared__ float Wls[F_IN * H_DIM];
    __shared__ float Wrs[F_IN * H_DIM];
    __shared__ float xs[LIN_NODES * F_IN];
    int t = threadIdx.x;
    for (int i = t; i < F_IN * H_DIM; i += 256) { Wls[i] = Wl[i]; Wrs[i] = Wr[i]; }
    size_t base = (size_t)blockIdx.x * LIN_NODES;
    const float4* xg = (const float4*)(x + base * F_IN);
    float4* xs4 = (float4*)xs;
    xs4[t] = xg[t];
    xs4[t + 256] = xg[t + 256];
    __syncthreads();
    int nl = t >> 5, h = t & 31;
    float al0 = 0.f, ar0 = 0.f, al1 = 0.f, ar1 = 0.f;
    const float4* xa4 = (const float4*)(xs + nl * F_IN);
    const float4* xb4 = (const float4*)(xs + (nl + 8) * F_IN);
    #pragma unroll 8
    for (int f4 = 0; f4 < 32; ++f4) {
        float4 xa = xa4[f4], xb = xb4[f4];
        int fb = f4 * 4;
        float w;
        w = Wls[(fb + 0) * 32 + h]; al0 = fmaf(xa.x, w, al0); al1 = fmaf(xb.x, w, al1);
        w = Wls[(fb + 1) * 32 + h]; al0 = fmaf(xa.y, w, al0); al1 = fmaf(xb.y, w, al1);
        w = Wls[(fb + 2) * 32 + h]; al0 = fmaf(xa.z, w, al0); al1 = fmaf(xb.z, w, al1);
        w = Wls[(fb + 3) * 32 + h]; al0 = fmaf(xa.w, w, al0); al1 = fmaf(xb.w, w, al1);
        w = Wrs[(fb + 0) * 32 + h]; ar0 = fmaf(xa.x, w, ar0); ar1 = fmaf(xb.x, w, ar1);
        w = Wrs[(fb + 1) * 32 + h]; ar0 = fmaf(xa.y, w, ar0); ar1 = fmaf(xb.y, w, ar1);
        w = Wrs[(fb + 2) * 32 + h]; ar0 = fmaf(xa.z, w, ar0); ar1 = fmaf(xb.z, w, ar1);
        w = Wrs[(fb + 3) * 32 + h]; ar0 = fmaf(xa.w, w, ar0); ar1 = fmaf(xb.w, w, ar1);
    }
    size_t n0 = base + nl, n1 = base + nl + 8;
    xl[n0 * 32 + h] = al0; xr[n0 * 32 + h] = ar0;
    xl[n1 * 32 + h] = al1; xr[n1 * 32 + h] = ar1;
}

// K2: one-pass edge binning into 1000 fine bins (100 dst nodes each).
// Block-local LDS counting sort; block-aggregated global atomics (64B-padded);
// staged flush gives coalesced runs per bin.
// Packed u32: (dst_local << 17) | src   (src < 2^17, dst_local < 2^7).
__global__ __launch_bounds__(1024) void k_part(
    const int* __restrict__ ei, int* __restrict__ bcnt, unsigned* __restrict__ binbuf)
{
    __shared__ int lcnt[1024];
    __shared__ int sc[1024];
    __shared__ int lbase[1024];
    __shared__ unsigned staged[PART_E];
    __shared__ unsigned short sbin[PART_E];
    int t = threadIdx.x;
    lcnt[t] = 0;
    __syncthreads();
    int i = blockIdx.x * PART_T + t;
    bool valid = i < N_EDGES / 4;
    int4 s4, d4;
    int b0 = 0, b1 = 0, b2 = 0, b3 = 0, o0 = 0, o1 = 0, o2 = 0, o3 = 0;
    if (valid) {
        s4 = ((const int4*)ei)[i];
        d4 = ((const int4*)(ei + N_EDGES))[i];
        b0 = d4.x / FBIN_SZ; b1 = d4.y / FBIN_SZ;
        b2 = d4.z / FBIN_SZ; b3 = d4.w / FBIN_SZ;
        o0 = atomicAdd(&lcnt[b0], 1);
        o1 = atomicAdd(&lcnt[b1], 1);
        o2 = atomicAdd(&lcnt[b2], 1);
        o3 = atomicAdd(&lcnt[b3], 1);
    }
    __syncthreads();
    sc[t] = lcnt[t];
    __syncthreads();
    for (int off = 1; off < 1024; off <<= 1) {     // inclusive scan (Hillis-Steele)
        int v = (t >= off) ? sc[t - off] : 0;
        __syncthreads();
        sc[t] += v;
        __syncthreads();
    }
    if (t < N_FBIN && lcnt[t] > 0) lbase[t] = atomicAdd(&bcnt[t * CPAD], lcnt[t]);
    if (valid) {
        int p;
        p = sc[b0] - lcnt[b0] + o0;
        staged[p] = ((unsigned)(d4.x - b0 * FBIN_SZ) << 17) | (unsigned)s4.x; sbin[p] = (unsigned short)b0;
        p = sc[b1] - lcnt[b1] + o1;
        staged[p] = ((unsigned)(d4.y - b1 * FBIN_SZ) << 17) | (unsigned)s4.y; sbin[p] = (unsigned short)b1;
        p = sc[b2] - lcnt[b2] + o2;
        staged[p] = ((unsigned)(d4.z - b2 * FBIN_SZ) << 17) | (unsigned)s4.z; sbin[p] = (unsigned short)b2;
        p = sc[b3] - lcnt[b3] + o3;
        staged[p] = ((unsigned)(d4.w - b3 * FBIN_SZ) << 17) | (unsigned)s4.w; sbin[p] = (unsigned short)b3;
    }
    __syncthreads();
    int total = sc[1023];
    for (int k = t; k < total; k += PART_T) {
        int b = sbin[k];
        binbuf[(size_t)b * BIN_CAP + lbase[b] + (k - (sc[b] - lcnt[b]))] = staged[k];
    }
}

// K3: per-bin in-LDS CSR build + fused score/softmax/aggregate/pool.
// Block = one bin (100 dst nodes, <=4096 edges). Phase 1: LDS counting sort
// by dst_local. Phase 2: half-wave = node, two 16-lane edge-streams per node,
// lane = h-pair (float2). Score: in-lane 2-wide dot + 4-step shfl butterfly
// within 16 lanes. 4 edges in flight per wave x 2-deep unroll per stream.
__global__ __launch_bounds__(512) void k_aggregate(
    const unsigned* __restrict__ binbuf, const int* __restrict__ bcnt,
    const float* __restrict__ xl, const float* __restrict__ xr,
    const float* __restrict__ att, const float* __restrict__ bias,
    const int* __restrict__ batch, unsigned* __restrict__ gu)
{
    __shared__ unsigned eL[BIN_CAP];      // 16 KB sorted edge list
    __shared__ int cnt[128];
    __shared__ int sc[128];
    __shared__ int cur[128];
    __shared__ unsigned lmax[64];         // bin spans <= 2 graphs (100 < 390)
    int t = threadIdx.x;
    int bin = blockIdx.x;
    int n_e = bcnt[bin * CPAD];
    const unsigned* bb = binbuf + (size_t)bin * BIN_CAP;

    if (t < 128) cnt[t] = 0;
    if (t < 64) lmax[t] = 0u;             // encodes -inf
    __syncthreads();
    for (int i = t; i < n_e; i += 512)
        atomicAdd(&cnt[bb[i] >> 17], 1);
    __syncthreads();
    if (t < 128) sc[t] = cnt[t];
    __syncthreads();
    for (int off = 1; off < 128; off <<= 1) {   // inclusive scan over 128
        int v = 0;
        if (t < 128 && t >= off) v = sc[t - off];
        __syncthreads();
        if (t < 128) sc[t] += v;
        __syncthreads();
    }
    if (t < 128) cur[t] = sc[t] - cnt[t];
    __syncthreads();
    for (int i = t; i < n_e; i += 512) {
        unsigned u = bb[i];
        int p = atomicAdd(&cur[u >> 17], 1);
        eL[p] = u;
    }
    __syncthreads();

    int lane = t & 63;
    int wv = t >> 6;                      // wave 0..7
    int half = lane >> 5;                 // node slot in wave
    int gid = (lane >> 4) & 1;            // edge-stream 0/1
    int hp = lane & 15;                   // h-pair: handles h = 2*hp, 2*hp+1
    const float2 a2 = ((const float2*)att)[hp];
    const float2 b2 = ((const float2*)bias)[hp];
    int lg0 = batch[bin * FBIN_SZ];

    for (int nl = wv * 2 + half; nl < FBIN_SZ; nl += 16) {
        int n = bin * FBIN_SZ + nl;
        int e0 = (nl > 0) ? sc[nl - 1] : 0;
        int e1 = sc[nl];
        const float2 xr2 = ((const float2*)(xr + (size_t)n * H_DIM))[hp];
        const float2 xl2 = ((const float2*)(xl + (size_t)n * H_DIM))[hp];

        // self-loop score (same value in both streams; credited to stream 0)
        float vx = xl2.x + xr2.x; vx = fmaxf(vx, vx * NEG);
        float vy = xl2.y + xr2.y; vy = fmaxf(vy, vy * NEG);
        float pr = vx * a2.x; pr = fmaf(vy, a2.y, pr);
        pr += __shfl_xor(pr, 1); pr += __shfl_xor(pr, 2);
        pr += __shfl_xor(pr, 4); pr += __shfl_xor(pr, 8);
        float z = 0.f; float2 acc = make_float2(0.f, 0.f);
        if (gid == 0) {
            float p = __expf(fminf(pr, 70.f));
            z = p; acc.x = p * xl2.x; acc.y = p * xl2.y;
        }

        int j = e0 + gid;
        for (; j + 2 < e1; j += 4) {                // 2-deep unroll per stream
            unsigned uA = eL[j], uB = eL[j + 2];
            int sA = (int)(uA & 0x1FFFFu), sB = (int)(uB & 0x1FFFFu);
            float2 xA = ((const float2*)(xl + (size_t)sA * H_DIM))[hp];
            float2 xB = ((const float2*)(xl + (size_t)sB * H_DIM))[hp];
            float ax = xA.x + xr2.x; ax = fmaxf(ax, ax * NEG);
            float ay = xA.y + xr2.y; ay = fmaxf(ay, ay * NEG);
            float bx = xB.x + xr2.x; bx = fmaxf(bx, bx * NEG);
            float by = xB.y + xr2.y; by = fmaxf(by, by * NEG);
            float pA = ax * a2.x; pA = fmaf(ay, a2.y, pA);
            float pB = bx * a2.x; pB = fmaf(by, a2.y, pB);
            pA += __shfl_xor(pA, 1); pB += __shfl_xor(pB, 1);
            pA += __shfl_xor(pA, 2); pB += __shfl_xor(pB, 2);
            pA += __shfl_xor(pA, 4); pB += __shfl_xor(pB, 4);
            pA += __shfl_xor(pA, 8); pB += __shfl_xor(pB, 8);
            float eA = __expf(fminf(pA, 70.f));
            float eB = __expf(fminf(pB, 70.f));
            z += eA + eB;
            acc.x = fmaf(eA, xA.x, acc.x); acc.y = fmaf(eA, xA.y, acc.y);
            acc.x = fmaf(eB, xB.x, acc.x); acc.y = fmaf(eB, xB.y, acc.y);
        }
        for (; j < e1; j += 2) {
            unsigned u = eL[j];
            int s = (int)(u & 0x1FFFFu);
            float2 xs2 = ((const float2*)(xl + (size_t)s * H_DIM))[hp];
            float ex = xs2.x + xr2.x; ex = fmaxf(ex, ex * NEG);
            float ey = xs2.y + xr2.y; ey = fmaxf(ey, ey * NEG);
            float pp = ex * a2.x; pp = fmaf(ey, a2.y, pp);
            pp += __shfl_xor(pp, 1); pp += __shfl_xor(pp, 2);
            pp += __shfl_xor(pp, 4); pp += __shfl_xor(pp, 8);
            float p = __expf(fminf(pp, 70.f));
            z += p;
            acc.x = fmaf(p, xs2.x, acc.x);
            acc.y = fmaf(p, xs2.y, acc.y);
        }

        // combine the two 16-lane streams
        z += __shfl_xor(z, 16);
        acc.x += __shfl_xor(acc.x, 16);
        acc.y += __shfl_xor(acc.y, 16);

        if (gid == 0) {
            float inv = 1.f / z;
            float ox = fmaf(acc.x, inv, b2.x);
            float oy = fmaf(acc.y, inv, b2.y);
            int gi = batch[n] - lg0;      // 0 or 1
            atomicMax(&lmax[gi * 32 + hp * 2 + 0], fenc(ox));
            atomicMax(&lmax[gi * 32 + hp * 2 + 1], fenc(oy));
        }
    }
    __syncthreads();
    if (t < 64) {                         // flush <=2 graphs to global
        int g = lg0 + (t >> 5);
        int glast = batch[bin * FBIN_SZ + FBIN_SZ - 1];
        if (g <= glast) atomicMax(&gu[g * H_DIM + (t & 31)], lmax[t]);
    }
}

// K4: h1 = relu(g @ W1 + b1)
__global__ __launch_bounds__(256) void k_mlp1(
    const unsigned* __restrict__ gu, const float* __restrict__ W1,
    const float* __restrict__ b1, float* __restrict__ h1)
{
    __shared__ float gs[H_DIM];
    int b = blockIdx.x, t = threadIdx.x;
    if (t < H_DIM) gs[t] = fdec(gu[b * H_DIM + t]);
    __syncthreads();
    for (int jj = 0; jj < 4; ++jj) {
        int j = jj * 256 + t;
        float a = b1[j];
        #pragma unroll
        for (int k = 0; k < H_DIM; ++k) a = fmaf(gs[k], W1[k * 1024 + j], a);
        h1[(size_t)b * 1024 + j] = fmaxf(a, 0.f);
    }
}

// K5: h2 = relu(h1 @ W2 + b2), 4 graphs per block
__global__ __launch_bounds__(512) void k_mlp2(
    const float* __restrict__ h1, const float* __restrict__ W2,
    const float* __restrict__ b2, float* __restrict__ h2)
{
    __shared__ float hs[4][1024];
    int b0 = blockIdx.x * 4, t = threadIdx.x;
    for (int r = 0; r < 4; ++r)
        for (int k = t; k < 1024; k += 512) hs[r][k] = h1[(size_t)(b0 + r) * 1024 + k];
    __syncthreads();
    float bb = b2[t];
    float a0 = bb, a1 = bb, a2 = bb, a3 = bb;
    for (int k = 0; k < 1024; ++k) {
        float w = W2[(size_t)k * 512 + t];
        a0 = fmaf(hs[0][k], w, a0);
        a1 = fmaf(hs[1][k], w, a1);
        a2 = fmaf(hs[2][k], w, a2);
        a3 = fmaf(hs[3][k], w, a3);
    }
    h2[(size_t)(b0 + 0) * 512 + t] = fmaxf(a0, 0.f);
    h2[(size_t)(b0 + 1) * 512 + t] = fmaxf(a1, 0.f);
    h2[(size_t)(b0 + 2) * 512 + t] = fmaxf(a2, 0.f);
    h2[(size_t)(b0 + 3) * 512 + t] = fmaxf(a3, 0.f);
}

// K6: out = h2 @ W3 + b3
__global__ __launch_bounds__(256) void k_mlp3(
    const float* __restrict__ h2, const float* __restrict__ W3,
    const float* __restrict__ b3, float* __restrict__ out)
{
    int b = blockIdx.x, t = threadIdx.x;
    int c = t >> 6, lane = t & 63;
    float a = 0.f;
    for (int k = lane; k < 512; k += 64)
        a = fmaf(h2[(size_t)b * 512 + k], W3[k * 4 + c], a);
    for (int off = 32; off; off >>= 1) a += __shfl_down(a, off);
    if (lane == 0) out[b * 4 + c] = a + b3[c];
}

extern "C" void kernel_launch(void* const* d_in, const int* in_sizes, int n_in,
                              void* d_out, int out_size, void* d_ws, size_t ws_size,
                              hipStream_t stream)
{
    const float* x     = (const float*)d_in[0];
    const int*   ei    = (const int*)d_in[1];
    const int*   batch = (const int*)d_in[2];
    const float* Wl    = (const float*)d_in[3];
    const float* Wr    = (const float*)d_in[4];
    const float* att   = (const float*)d_in[5];
    const float* bias  = (const float*)d_in[6];
    const float* W1    = (const float*)d_in[7];
    const float* b1    = (const float*)d_in[8];
    const float* W2    = (const float*)d_in[9];
    const float* b2    = (const float*)d_in[10];
    const float* W3    = (const float*)d_in[11];
    const float* b3    = (const float*)d_in[12];
    float* out = (float*)d_out;

    // workspace layout (~44 MB)
    float*    xl     = (float*)d_ws;                               // 3.2M f
    float*    xr     = xl + (size_t)N_NODES * H_DIM;               // 3.2M f
    unsigned* binbuf = (unsigned*)(xr + (size_t)N_NODES * H_DIM);  // 1000*4096
    int*      bcnt   = (int*)(binbuf + (size_t)N_FBIN * BIN_CAP);  // 16384 [memset]
    unsigned* gu     = (unsigned*)(bcnt + N_FBIN * CPAD);          // 8192  [memset]
    float*    h1     = (float*)(gu + B_GR * H_DIM);                // 262144
    float*    h2     = h1 + (size_t)B_GR * 1024;                   // 131072

    hipMemsetAsync(bcnt, 0, (size_t)(N_FBIN * CPAD + B_GR * H_DIM) * sizeof(int), stream);

    k_part  <<<PART_NBLK, PART_T, 0, stream>>>(ei, bcnt, binbuf);
    k_linear<<<N_NODES / LIN_NODES, 256, 0, stream>>>(x, Wl, Wr, xl, xr);
    k_aggregate<<<N_FBIN, 512, 0, stream>>>(binbuf, bcnt, xl, xr, att, bias, batch, gu);
    k_mlp1<<<B_GR, 256, 0, stream>>>(gu, W1, b1, h1);
    k_mlp2<<<B_GR / 4, 512, 0, stream>>>(h1, W2, b2, h2);
    k_mlp3<<<B_GR, 256, 0, stream>>>(h2, W3, b3, out);
}

// Round 11
// 212.985 us; speedup vs baseline: 3.3513x; 1.0994x over previous
//
#include <hip/hip_runtime.h>

#define N_NODES 100000
#define N_EDGES 3200000
#define F_IN    128
#define H_DIM   32
#define B_GR    256
#define NEG     0.2f

#define FBIN_SZ  100
#define N_FBIN   (N_NODES / FBIN_SZ)        // 1000
#define BIN_CAP  4096                        // mean 3200, +15.8 sigma
#define CPAD     16                          // bcnt 64B padding
#define PART_T   1024
#define PART_NBLK ((N_EDGES / 4 + PART_T - 1) / PART_T)  // 782
#define LIN_BLK  ((N_NODES + 63) / 64)       // 1563 (64 nodes/block)

// ---- monotonic float<->uint encoding for atomicMax on floats ----
__device__ __forceinline__ unsigned fenc(float f) {
    unsigned u = __float_as_uint(f);
    return (u & 0x80000000u) ? ~u : (u | 0x80000000u);
}
__device__ __forceinline__ float fdec(unsigned u) {
    return (u & 0x80000000u) ? __uint_as_float(u & 0x7FFFFFFFu)
                             : __uint_as_float(~u);
}

// K1: fat kernel. Blocks [0, PART_NBLK): one-pass edge binning (LDS counting
// sort, wave-shfl scan, coalesced staged flush). Blocks [PART_NBLK, +LIN_BLK):
// xl = x@Wl, xr = x@Wr as 4 x 256-thread quarters sharing W tiles.
// Both paths are independent -> they co-schedule across CUs in one dispatch.
__global__ __launch_bounds__(1024) void k_fused(
    const int* __restrict__ ei, int* __restrict__ bcnt, unsigned* __restrict__ binbuf,
    const float* __restrict__ x, const float* __restrict__ Wl,
    const float* __restrict__ Wr, float* __restrict__ xl, float* __restrict__ xr)
{
    __shared__ __align__(16) float smem[16384];   // 64 KB union
    int t = threadIdx.x;

    if (blockIdx.x < PART_NBLK) {
        // ---------------- edge binning ----------------
        int* lcnt = (int*)smem;                       // 1024
        int* sc   = lcnt + 1024;                      // 1024
        int* lbase = sc + 1024;                       // 1024
        unsigned* staged = (unsigned*)(lbase + 1024); // 4096
        unsigned short* sbin = (unsigned short*)(staged + 4096); // 4096 u16
        int* wsum = (int*)(sbin + 4096);              // 16

        lcnt[t] = 0;
        __syncthreads();
        int i = blockIdx.x * PART_T + t;
        bool valid = i < N_EDGES / 4;
        int4 s4, d4;
        int b0 = 0, b1 = 0, b2 = 0, b3 = 0, o0 = 0, o1 = 0, o2 = 0, o3 = 0;
        if (valid) {
            s4 = ((const int4*)ei)[i];
            d4 = ((const int4*)(ei + N_EDGES))[i];
            b0 = d4.x / FBIN_SZ; b1 = d4.y / FBIN_SZ;
            b2 = d4.z / FBIN_SZ; b3 = d4.w / FBIN_SZ;
            o0 = atomicAdd(&lcnt[b0], 1);
            o1 = atomicAdd(&lcnt[b1], 1);
            o2 = atomicAdd(&lcnt[b2], 1);
            o3 = atomicAdd(&lcnt[b3], 1);
        }
        __syncthreads();
        // wave-level inclusive scan of lcnt (16 waves x 64 lanes)
        int lane = t & 63, w = t >> 6;
        int inc = lcnt[t];
        #pragma unroll
        for (int off = 1; off < 64; off <<= 1) {
            int v = __shfl_up(inc, off);
            if (lane >= off) inc += v;
        }
        if (lane == 63) wsum[w] = inc;
        __syncthreads();
        if (t == 0) {
            int run = 0;
            #pragma unroll
            for (int k = 0; k < 16; ++k) { int v = wsum[k]; wsum[k] = run; run += v; }
        }
        __syncthreads();
        sc[t] = inc + wsum[w];
        __syncthreads();
        if (t < N_FBIN && lcnt[t] > 0) lbase[t] = atomicAdd(&bcnt[t * CPAD], lcnt[t]);
        if (valid) {
            int p;
            p = sc[b0] - lcnt[b0] + o0;
            staged[p] = ((unsigned)(d4.x - b0 * FBIN_SZ) << 17) | (unsigned)s4.x; sbin[p] = (unsigned short)b0;
            p = sc[b1] - lcnt[b1] + o1;
            staged[p] = ((unsigned)(d4.y - b1 * FBIN_SZ) << 17) | (unsigned)s4.y; sbin[p] = (unsigned short)b1;
            p = sc[b2] - lcnt[b2] + o2;
            staged[p] = ((unsigned)(d4.z - b2 * FBIN_SZ) << 17) | (unsigned)s4.z; sbin[p] = (unsigned short)b2;
            p = sc[b3] - lcnt[b3] + o3;
            staged[p] = ((unsigned)(d4.w - b3 * FBIN_SZ) << 17) | (unsigned)s4.w; sbin[p] = (unsigned short)b3;
        }
        __syncthreads();
        int total = sc[1023];
        for (int k = t; k < total; k += PART_T) {
            int b = sbin[k];
            binbuf[(size_t)b * BIN_CAP + lbase[b] + (k - (sc[b] - lcnt[b]))] = staged[k];
        }
    } else {
        // ---------------- linear: xl/xr ----------------
        float* Wls = smem;            // 4096
        float* Wrs = smem + 4096;     // 4096
        float* xsb = smem + 8192;     // 4 x 2048
        int blk = blockIdx.x - PART_NBLK;
        for (int i = t; i < F_IN * H_DIM; i += 1024) { Wls[i] = Wl[i]; Wrs[i] = Wr[i]; }
        int q = t >> 8, tq = t & 255;
        size_t base = (size_t)blk * 64 + q * 16;
        bool act = base < N_NODES;     // quarters are 16-aligned; all-or-nothing
        float* xs = xsb + q * 2048;
        if (act) {
            const float4* xg = (const float4*)(x + base * F_IN);
            float4* xs4 = (float4*)xs;
            xs4[tq] = xg[tq];
            xs4[tq + 256] = xg[tq + 256];
        }
        __syncthreads();
        if (act) {
            int nl = tq >> 5, h = tq & 31;
            float al0 = 0.f, ar0 = 0.f, al1 = 0.f, ar1 = 0.f;
            const float4* xa4 = (const float4*)(xs + nl * F_IN);
            const float4* xb4 = (const float4*)(xs + (nl + 8) * F_IN);
            #pragma unroll 8
            for (int f4 = 0; f4 < 32; ++f4) {
                float4 xa = xa4[f4], xb = xb4[f4];
                int fb = f4 * 4;
                float w;
                w = Wls[(fb + 0) * 32 + h]; al0 = fmaf(xa.x, w, al0); al1 = fmaf(xb.x, w, al1);
                w = Wls[(fb + 1) * 32 + h]; al0 = fmaf(xa.y, w, al0); al1 = fmaf(xb.y, w, al1);
                w = Wls[(fb + 2) * 32 + h]; al0 = fmaf(xa.z, w, al0); al1 = fmaf(xb.z, w, al1);
                w = Wls[(fb + 3) * 32 + h]; al0 = fmaf(xa.w, w, al0); al1 = fmaf(xb.w, w, al1);
                w = Wrs[(fb + 0) * 32 + h]; ar0 = fmaf(xa.x, w, ar0); ar1 = fmaf(xb.x, w, ar1);
                w = Wrs[(fb + 1) * 32 + h]; ar0 = fmaf(xa.y, w, ar0); ar1 = fmaf(xb.y, w, ar1);
                w = Wrs[(fb + 2) * 32 + h]; ar0 = fmaf(xa.z, w, ar0); ar1 = fmaf(xb.z, w, ar1);
                w = Wrs[(fb + 3) * 32 + h]; ar0 = fmaf(xa.w, w, ar0); ar1 = fmaf(xb.w, w, ar1);
            }
            size_t n0 = base + nl, n1 = base + nl + 8;
            xl[n0 * 32 + h] = al0; xr[n0 * 32 + h] = ar0;
            xl[n1 * 32 + h] = al1; xr[n1 * 32 + h] = ar1;
        }
    }
}

// K2: per-bin in-LDS CSR build + fused score/softmax/aggregate/pool (r10).
__global__ __launch_bounds__(512) void k_aggregate(
    const unsigned* __restrict__ binbuf, const int* __restrict__ bcnt,
    const float* __restrict__ xl, const float* __restrict__ xr,
    const float* __restrict__ att, const float* __restrict__ bias,
    const int* __restrict__ batch, unsigned* __restrict__ gu)
{
    __shared__ unsigned eL[BIN_CAP];      // 16 KB sorted edge list
    __shared__ int cnt[128];
    __shared__ int sc[128];
    __shared__ int cur[128];
    __shared__ unsigned lmax[64];         // bin spans <= 2 graphs (100 < 390)
    int t = threadIdx.x;
    int bin = blockIdx.x;
    int n_e = bcnt[bin * CPAD];
    const unsigned* bb = binbuf + (size_t)bin * BIN_CAP;

    if (t < 128) cnt[t] = 0;
    if (t < 64) lmax[t] = 0u;             // encodes -inf
    __syncthreads();
    for (int i = t; i < n_e; i += 512)
        atomicAdd(&cnt[bb[i] >> 17], 1);
    __syncthreads();
    if (t < 128) sc[t] = cnt[t];
    __syncthreads();
    for (int off = 1; off < 128; off <<= 1) {
        int v = 0;
        if (t < 128 && t >= off) v = sc[t - off];
        __syncthreads();
        if (t < 128) sc[t] += v;
        __syncthreads();
    }
    if (t < 128) cur[t] = sc[t] - cnt[t];
    __syncthreads();
    for (int i = t; i < n_e; i += 512) {
        unsigned u = bb[i];
        int p = atomicAdd(&cur[u >> 17], 1);
        eL[p] = u;
    }
    __syncthreads();

    int lane = t & 63;
    int wv = t >> 6;
    int half = lane >> 5;
    int gid = (lane >> 4) & 1;
    int hp = lane & 15;
    const float2 a2 = ((const float2*)att)[hp];
    const float2 b2 = ((const float2*)bias)[hp];
    int lg0 = batch[bin * FBIN_SZ];

    for (int nl = wv * 2 + half; nl < FBIN_SZ; nl += 16) {
        int n = bin * FBIN_SZ + nl;
        int e0 = (nl > 0) ? sc[nl - 1] : 0;
        int e1 = sc[nl];
        const float2 xr2 = ((const float2*)(xr + (size_t)n * H_DIM))[hp];
        const float2 xl2 = ((const float2*)(xl + (size_t)n * H_DIM))[hp];

        float vx = xl2.x + xr2.x; vx = fmaxf(vx, vx * NEG);
        float vy = xl2.y + xr2.y; vy = fmaxf(vy, vy * NEG);
        float pr = vx * a2.x; pr = fmaf(vy, a2.y, pr);
        pr += __shfl_xor(pr, 1); pr += __shfl_xor(pr, 2);
        pr += __shfl_xor(pr, 4); pr += __shfl_xor(pr, 8);
        float z = 0.f; float2 acc = make_float2(0.f, 0.f);
        if (gid == 0) {
            float p = __expf(fminf(pr, 70.f));
            z = p; acc.x = p * xl2.x; acc.y = p * xl2.y;
        }

        int j = e0 + gid;
        for (; j + 2 < e1; j += 4) {
            unsigned uA = eL[j], uB = eL[j + 2];
            int sA = (int)(uA & 0x1FFFFu), sB = (int)(uB & 0x1FFFFu);
            float2 xA = ((const float2*)(xl + (size_t)sA * H_DIM))[hp];
            float2 xB = ((const float2*)(xl + (size_t)sB * H_DIM))[hp];
            float ax = xA.x + xr2.x; ax = fmaxf(ax, ax * NEG);
            float ay = xA.y + xr2.y; ay = fmaxf(ay, ay * NEG);
            float bx = xB.x + xr2.x; bx = fmaxf(bx, bx * NEG);
            float by = xB.y + xr2.y; by = fmaxf(by, by * NEG);
            float pA = ax * a2.x; pA = fmaf(ay, a2.y, pA);
            float pB = bx * a2.x; pB = fmaf(by, a2.y, pB);
            pA += __shfl_xor(pA, 1); pB += __shfl_xor(pB, 1);
            pA += __shfl_xor(pA, 2); pB += __shfl_xor(pB, 2);
            pA += __shfl_xor(pA, 4); pB += __shfl_xor(pB, 4);
            pA += __shfl_xor(pA, 8); pB += __shfl_xor(pB, 8);
            float eA = __expf(fminf(pA, 70.f));
            float eB = __expf(fminf(pB, 70.f));
            z += eA + eB;
            acc.x = fmaf(eA, xA.x, acc.x); acc.y = fmaf(eA, xA.y, acc.y);
            acc.x = fmaf(eB, xB.x, acc.x); acc.y = fmaf(eB, xB.y, acc.y);
        }
        for (; j < e1; j += 2) {
            unsigned u = eL[j];
            int s = (int)(u & 0x1FFFFu);
            float2 xs2 = ((const float2*)(xl + (size_t)s * H_DIM))[hp];
            float ex = xs2.x + xr2.x; ex = fmaxf(ex, ex * NEG);
            float ey = xs2.y + xr2.y; ey = fmaxf(ey, ey * NEG);
            float pp = ex * a2.x; pp = fmaf(ey, a2.y, pp);
            pp += __shfl_xor(pp, 1); pp += __shfl_xor(pp, 2);
            pp += __shfl_xor(pp, 4); pp += __shfl_xor(pp, 8);
            float p = __expf(fminf(pp, 70.f));
            z += p;
            acc.x = fmaf(p, xs2.x, acc.x);
            acc.y = fmaf(p, xs2.y, acc.y);
        }

        z += __shfl_xor(z, 16);
        acc.x += __shfl_xor(acc.x, 16);
        acc.y += __shfl_xor(acc.y, 16);

        if (gid == 0) {
            float inv = 1.f / z;
            float ox = fmaf(acc.x, inv, b2.x);
            float oy = fmaf(acc.y, inv, b2.y);
            int gi = batch[n] - lg0;
            atomicMax(&lmax[gi * 32 + hp * 2 + 0], fenc(ox));
            atomicMax(&lmax[gi * 32 + hp * 2 + 1], fenc(oy));
        }
    }
    __syncthreads();
    if (t < 64) {
        int g = lg0 + (t >> 5);
        int glast = batch[bin * FBIN_SZ + FBIN_SZ - 1];
        if (g <= glast) atomicMax(&gu[g * H_DIM + (t & 31)], lmax[t]);
    }
}

// K3: fused MLP head, 4 graphs per block, h1/h2 staged in LDS.
__global__ __launch_bounds__(512) void k_head(
    const unsigned* __restrict__ gu, const float* __restrict__ W1,
    const float* __restrict__ b1, const float* __restrict__ W2,
    const float* __restrict__ b2, const float* __restrict__ W3,
    const float* __restrict__ b3, float* __restrict__ out)
{
    __shared__ float gs[4][H_DIM];
    __shared__ float h1s[4][1024];
    __shared__ float h2s[4][512];
    int b0 = blockIdx.x * 4, t = threadIdx.x;
    if (t < 128) gs[t >> 5][t & 31] = fdec(gu[b0 * H_DIM + t]);
    __syncthreads();
    #pragma unroll
    for (int jj = 0; jj < 2; ++jj) {        // h1: 1024 cols, 4 graphs
        int j = jj * 512 + t;
        float a0 = b1[j], a1 = a0, a2 = a0, a3 = a0;
        #pragma unroll
        for (int k = 0; k < H_DIM; ++k) {
            float w = W1[k * 1024 + j];
            a0 = fmaf(gs[0][k], w, a0);
            a1 = fmaf(gs[1][k], w, a1);
            a2 = fmaf(gs[2][k], w, a2);
            a3 = fmaf(gs[3][k], w, a3);
        }
        h1s[0][j] = fmaxf(a0, 0.f);
        h1s[1][j] = fmaxf(a1, 0.f);
        h1s[2][j] = fmaxf(a2, 0.f);
        h1s[3][j] = fmaxf(a3, 0.f);
    }
    __syncthreads();
    {                                        // h2: 512 cols, 4 graphs
        float bb = b2[t];
        float a0 = bb, a1 = bb, a2 = bb, a3 = bb;
        for (int k = 0; k < 1024; ++k) {
            float w = W2[(size_t)k * 512 + t];
            a0 = fmaf(h1s[0][k], w, a0);
            a1 = fmaf(h1s[1][k], w, a1);
            a2 = fmaf(h1s[2][k], w, a2);
            a3 = fmaf(h1s[3][k], w, a3);
        }
        h2s[0][t] = fmaxf(a0, 0.f);
        h2s[1][t] = fmaxf(a1, 0.f);
        h2s[2][t] = fmaxf(a2, 0.f);
        h2s[3][t] = fmaxf(a3, 0.f);
    }
    __syncthreads();
    {                                        // out: 16 (g,c) pairs x 32 lanes
        int pair = t >> 5, lane = t & 31;
        int g = pair >> 2, c = pair & 3;
        float a = 0.f;
        for (int k = lane; k < 512; k += 32)
            a = fmaf(h2s[g][k], W3[k * 4 + c], a);
        a += __shfl_xor(a, 16); a += __shfl_xor(a, 8);
        a += __shfl_xor(a, 4);  a += __shfl_xor(a, 2); a += __shfl_xor(a, 1);
        if (lane == 0) out[(b0 + g) * 4 + c] = a + b3[c];
    }
}

extern "C" void kernel_launch(void* const* d_in, const int* in_sizes, int n_in,
                              void* d_out, int out_size, void* d_ws, size_t ws_size,
                              hipStream_t stream)
{
    const float* x     = (const float*)d_in[0];
    const int*   ei    = (const int*)d_in[1];
    const int*   batch = (const int*)d_in[2];
    const float* Wl    = (const float*)d_in[3];
    const float* Wr    = (const float*)d_in[4];
    const float* att   = (const float*)d_in[5];
    const float* bias  = (const float*)d_in[6];
    const float* W1    = (const float*)d_in[7];
    const float* b1    = (const float*)d_in[8];
    const float* W2    = (const float*)d_in[9];
    const float* b2    = (const float*)d_in[10];
    const float* W3    = (const float*)d_in[11];
    const float* b3    = (const float*)d_in[12];
    float* out = (float*)d_out;

    // workspace layout (~42 MB)
    float*    xl     = (float*)d_ws;                               // 3.2M f
    float*    xr     = xl + (size_t)N_NODES * H_DIM;               // 3.2M f
    unsigned* binbuf = (unsigned*)(xr + (size_t)N_NODES * H_DIM);  // 1000*4096
    int*      bcnt   = (int*)(binbuf + (size_t)N_FBIN * BIN_CAP);  // 16384 [memset]
    unsigned* gu     = (unsigned*)(bcnt + N_FBIN * CPAD);          // 8192  [memset]

    hipMemsetAsync(bcnt, 0, (size_t)(N_FBIN * CPAD + B_GR * H_DIM) * sizeof(int), stream);

    k_fused<<<PART_NBLK + LIN_BLK, 1024, 0, stream>>>(
        ei, bcnt, binbuf, x, Wl, Wr, xl, xr);
    k_aggregate<<<N_FBIN, 512, 0, stream>>>(binbuf, bcnt, xl, xr, att, bias, batch, gu);
    k_head<<<B_GR / 4, 512, 0, stream>>>(gu, W1, b1, W2, b2, W3, b3, out);
}

// Round 12
// 203.384 us; speedup vs baseline: 3.5095x; 1.0472x over previous
//
#include <hip/hip_runtime.h>

#define N_NODES 100000
#define N_EDGES 3200000
#define F_IN    128
#define H_DIM   32
#define B_GR    256
#define NEG     0.2f

#define FBIN_SZ  100
#define N_FBIN   (N_NODES / FBIN_SZ)        // 1000
#define BIN_CAP  4096                        // mean 3200, +15.8 sigma
#define CPAD     16                          // bcnt 64B padding
#define PART_T   1024
#define EPB_G    2048                        // int4 groups per binning block (8192 edges)
#define PART_NBLK ((N_EDGES / 4 + EPB_G - 1) / EPB_G)   // 391
#define LIN_BLK  ((N_NODES + 63) / 64)       // 1563 (64 nodes/block)

// ---- monotonic float<->uint encoding for atomicMax on floats ----
__device__ __forceinline__ unsigned fenc(float f) {
    unsigned u = __float_as_uint(f);
    return (u & 0x80000000u) ? ~u : (u | 0x80000000u);
}
__device__ __forceinline__ float fdec(unsigned u) {
    return (u & 0x80000000u) ? __uint_as_float(u & 0x7FFFFFFFu)
                             : __uint_as_float(~u);
}

// K1: fat kernel. Blocks [0, PART_NBLK): two-pass direct-write edge binning
// (8192 edges/block held in registers; pass1 LDS count, 1 global atomic per
// touched bin, pass2 LDS-cursor + direct global write; 3 barriers, no scan,
// no staging). Blocks [PART_NBLK, +LIN_BLK): xl = x@Wl, xr = x@Wr as
// 4 x 256-thread quarters sharing W tiles. Independent -> co-scheduled.
__global__ __launch_bounds__(1024) void k_fused(
    const int* __restrict__ ei, int* __restrict__ bcnt, unsigned* __restrict__ binbuf,
    const float* __restrict__ x, const float* __restrict__ Wl,
    const float* __restrict__ Wr, float* __restrict__ xl, float* __restrict__ xr)
{
    __shared__ __align__(16) float smem[16384];   // 64 KB union
    int t = threadIdx.x;

    if (blockIdx.x < PART_NBLK) {
        // ---------------- edge binning (two-pass, register-held) ----------------
        int* lcnt = (int*)smem;           // 1024 ints (1000 used)
        int* cur  = lcnt + 1024;          // 1024 ints
        lcnt[t] = 0;
        __syncthreads();

        int g0 = blockIdx.x * EPB_G;
        int4 s4[2], d4[2];
        int bb_[2][4];
        bool val[2];
        #pragma unroll
        for (int r = 0; r < 2; ++r) {
            int i = g0 + r * PART_T + t;
            val[r] = i < N_EDGES / 4;
            if (val[r]) {
                s4[r] = ((const int4*)ei)[i];
                d4[r] = ((const int4*)(ei + N_EDGES))[i];
                bb_[r][0] = d4[r].x / FBIN_SZ;
                bb_[r][1] = d4[r].y / FBIN_SZ;
                bb_[r][2] = d4[r].z / FBIN_SZ;
                bb_[r][3] = d4[r].w / FBIN_SZ;
                atomicAdd(&lcnt[bb_[r][0]], 1);
                atomicAdd(&lcnt[bb_[r][1]], 1);
                atomicAdd(&lcnt[bb_[r][2]], 1);
                atomicAdd(&lcnt[bb_[r][3]], 1);
            }
        }
        __syncthreads();
        if (t < N_FBIN) {
            int c = lcnt[t];
            if (c > 0) cur[t] = atomicAdd(&bcnt[t * CPAD], c);
        }
        __syncthreads();
        #pragma unroll
        for (int r = 0; r < 2; ++r) {
            if (val[r]) {
                int b, p;
                b = bb_[r][0]; p = atomicAdd(&cur[b], 1);
                binbuf[(size_t)b * BIN_CAP + p] = ((unsigned)(d4[r].x - b * FBIN_SZ) << 17) | (unsigned)s4[r].x;
                b = bb_[r][1]; p = atomicAdd(&cur[b], 1);
                binbuf[(size_t)b * BIN_CAP + p] = ((unsigned)(d4[r].y - b * FBIN_SZ) << 17) | (unsigned)s4[r].y;
                b = bb_[r][2]; p = atomicAdd(&cur[b], 1);
                binbuf[(size_t)b * BIN_CAP + p] = ((unsigned)(d4[r].z - b * FBIN_SZ) << 17) | (unsigned)s4[r].z;
                b = bb_[r][3]; p = atomicAdd(&cur[b], 1);
                binbuf[(size_t)b * BIN_CAP + p] = ((unsigned)(d4[r].w - b * FBIN_SZ) << 17) | (unsigned)s4[r].w;
            }
        }
    } else {
        // ---------------- linear: xl/xr ----------------
        float* Wls = smem;            // 4096
        float* Wrs = smem + 4096;     // 4096
        float* xsb = smem + 8192;     // 4 x 2048
        int blk = blockIdx.x - PART_NBLK;
        for (int i = t; i < F_IN * H_DIM; i += 1024) { Wls[i] = Wl[i]; Wrs[i] = Wr[i]; }
        int q = t >> 8, tq = t & 255;
        size_t base = (size_t)blk * 64 + q * 16;
        bool act = base < N_NODES;     // quarters are 16-aligned; all-or-nothing
        float* xs = xsb + q * 2048;
        if (act) {
            const float4* xg = (const float4*)(x + base * F_IN);
            float4* xs4 = (float4*)xs;
            xs4[tq] = xg[tq];
            xs4[tq + 256] = xg[tq + 256];
        }
        __syncthreads();
        if (act) {
            int nl = tq >> 5, h = tq & 31;
            float al0 = 0.f, ar0 = 0.f, al1 = 0.f, ar1 = 0.f;
            const float4* xa4 = (const float4*)(xs + nl * F_IN);
            const float4* xb4 = (const float4*)(xs + (nl + 8) * F_IN);
            #pragma unroll 8
            for (int f4 = 0; f4 < 32; ++f4) {
                float4 xa = xa4[f4], xb = xb4[f4];
                int fb = f4 * 4;
                float w;
                w = Wls[(fb + 0) * 32 + h]; al0 = fmaf(xa.x, w, al0); al1 = fmaf(xb.x, w, al1);
                w = Wls[(fb + 1) * 32 + h]; al0 = fmaf(xa.y, w, al0); al1 = fmaf(xb.y, w, al1);
                w = Wls[(fb + 2) * 32 + h]; al0 = fmaf(xa.z, w, al0); al1 = fmaf(xb.z, w, al1);
                w = Wls[(fb + 3) * 32 + h]; al0 = fmaf(xa.w, w, al0); al1 = fmaf(xb.w, w, al1);
                w = Wrs[(fb + 0) * 32 + h]; ar0 = fmaf(xa.x, w, ar0); ar1 = fmaf(xb.x, w, ar1);
                w = Wrs[(fb + 1) * 32 + h]; ar0 = fmaf(xa.y, w, ar0); ar1 = fmaf(xb.y, w, ar1);
                w = Wrs[(fb + 2) * 32 + h]; ar0 = fmaf(xa.z, w, ar0); ar1 = fmaf(xb.z, w, ar1);
                w = Wrs[(fb + 3) * 32 + h]; ar0 = fmaf(xa.w, w, ar0); ar1 = fmaf(xb.w, w, ar1);
            }
            size_t n0 = base + nl, n1 = base + nl + 8;
            xl[n0 * 32 + h] = al0; xr[n0 * 32 + h] = ar0;
            xl[n1 * 32 + h] = al1; xr[n1 * 32 + h] = ar1;
        }
    }
}

// K2: per-bin in-LDS CSR build + fused score/softmax/aggregate/pool (r10).
__global__ __launch_bounds__(512) void k_aggregate(
    const unsigned* __restrict__ binbuf, const int* __restrict__ bcnt,
    const float* __restrict__ xl, const float* __restrict__ xr,
    const float* __restrict__ att, const float* __restrict__ bias,
    const int* __restrict__ batch, unsigned* __restrict__ gu)
{
    __shared__ unsigned eL[BIN_CAP];      // 16 KB sorted edge list
    __shared__ int cnt[128];
    __shared__ int sc[128];
    __shared__ int cur[128];
    __shared__ unsigned lmax[64];         // bin spans <= 2 graphs (100 < 390)
    int t = threadIdx.x;
    int bin = blockIdx.x;
    int n_e = bcnt[bin * CPAD];
    const unsigned* bb = binbuf + (size_t)bin * BIN_CAP;

    if (t < 128) cnt[t] = 0;
    if (t < 64) lmax[t] = 0u;             // encodes -inf
    __syncthreads();
    for (int i = t; i < n_e; i += 512)
        atomicAdd(&cnt[bb[i] >> 17], 1);
    __syncthreads();
    if (t < 128) sc[t] = cnt[t];
    __syncthreads();
    for (int off = 1; off < 128; off <<= 1) {
        int v = 0;
        if (t < 128 && t >= off) v = sc[t - off];
        __syncthreads();
        if (t < 128) sc[t] += v;
        __syncthreads();
    }
    if (t < 128) cur[t] = sc[t] - cnt[t];
    __syncthreads();
    for (int i = t; i < n_e; i += 512) {
        unsigned u = bb[i];
        int p = atomicAdd(&cur[u >> 17], 1);
        eL[p] = u;
    }
    __syncthreads();

    int lane = t & 63;
    int wv = t >> 6;
    int half = lane >> 5;
    int gid = (lane >> 4) & 1;
    int hp = lane & 15;
    const float2 a2 = ((const float2*)att)[hp];
    const float2 b2 = ((const float2*)bias)[hp];
    int lg0 = batch[bin * FBIN_SZ];

    for (int nl = wv * 2 + half; nl < FBIN_SZ; nl += 16) {
        int n = bin * FBIN_SZ + nl;
        int e0 = (nl > 0) ? sc[nl - 1] : 0;
        int e1 = sc[nl];
        const float2 xr2 = ((const float2*)(xr + (size_t)n * H_DIM))[hp];
        const float2 xl2 = ((const float2*)(xl + (size_t)n * H_DIM))[hp];

        float vx = xl2.x + xr2.x; vx = fmaxf(vx, vx * NEG);
        float vy = xl2.y + xr2.y; vy = fmaxf(vy, vy * NEG);
        float pr = vx * a2.x; pr = fmaf(vy, a2.y, pr);
        pr += __shfl_xor(pr, 1); pr += __shfl_xor(pr, 2);
        pr += __shfl_xor(pr, 4); pr += __shfl_xor(pr, 8);
        float z = 0.f; float2 acc = make_float2(0.f, 0.f);
        if (gid == 0) {
            float p = __expf(fminf(pr, 70.f));
            z = p; acc.x = p * xl2.x; acc.y = p * xl2.y;
        }

        int j = e0 + gid;
        for (; j + 2 < e1; j += 4) {
            unsigned uA = eL[j], uB = eL[j + 2];
            int sA = (int)(uA & 0x1FFFFu), sB = (int)(uB & 0x1FFFFu);
            float2 xA = ((const float2*)(xl + (size_t)sA * H_DIM))[hp];
            float2 xB = ((const float2*)(xl + (size_t)sB * H_DIM))[hp];
            float ax = xA.x + xr2.x; ax = fmaxf(ax, ax * NEG);
            float ay = xA.y + xr2.y; ay = fmaxf(ay, ay * NEG);
            float bx = xB.x + xr2.x; bx = fmaxf(bx, bx * NEG);
            float by = xB.y + xr2.y; by = fmaxf(by, by * NEG);
            float pA = ax * a2.x; pA = fmaf(ay, a2.y, pA);
            float pB = bx * a2.x; pB = fmaf(by, a2.y, pB);
            pA += __shfl_xor(pA, 1); pB += __shfl_xor(pB, 1);
            pA += __shfl_xor(pA, 2); pB += __shfl_xor(pB, 2);
            pA += __shfl_xor(pA, 4); pB += __shfl_xor(pB, 4);
            pA += __shfl_xor(pA, 8); pB += __shfl_xor(pB, 8);
            float eA = __expf(fminf(pA, 70.f));
            float eB = __expf(fminf(pB, 70.f));
            z += eA + eB;
            acc.x = fmaf(eA, xA.x, acc.x); acc.y = fmaf(eA, xA.y, acc.y);
            acc.x = fmaf(eB, xB.x, acc.x); acc.y = fmaf(eB, xB.y, acc.y);
        }
        for (; j < e1; j += 2) {
            unsigned u = eL[j];
            int s = (int)(u & 0x1FFFFu);
            float2 xs2 = ((const float2*)(xl + (size_t)s * H_DIM))[hp];
            float ex = xs2.x + xr2.x; ex = fmaxf(ex, ex * NEG);
            float ey = xs2.y + xr2.y; ey = fmaxf(ey, ey * NEG);
            float pp = ex * a2.x; pp = fmaf(ey, a2.y, pp);
            pp += __shfl_xor(pp, 1); pp += __shfl_xor(pp, 2);
            pp += __shfl_xor(pp, 4); pp += __shfl_xor(pp, 8);
            float p = __expf(fminf(pp, 70.f));
            z += p;
            acc.x = fmaf(p, xs2.x, acc.x);
            acc.y = fmaf(p, xs2.y, acc.y);
        }

        z += __shfl_xor(z, 16);
        acc.x += __shfl_xor(acc.x, 16);
        acc.y += __shfl_xor(acc.y, 16);

        if (gid == 0) {
            float inv = 1.f / z;
            float ox = fmaf(acc.x, inv, b2.x);
            float oy = fmaf(acc.y, inv, b2.y);
            int gi = batch[n] - lg0;
            atomicMax(&lmax[gi * 32 + hp * 2 + 0], fenc(ox));
            atomicMax(&lmax[gi * 32 + hp * 2 + 1], fenc(oy));
        }
    }
    __syncthreads();
    if (t < 64) {
        int g = lg0 + (t >> 5);
        int glast = batch[bin * FBIN_SZ + FBIN_SZ - 1];
        if (g <= glast) atomicMax(&gu[g * H_DIM + (t & 31)], lmax[t]);
    }
}

// K3: fused MLP head, 4 graphs per block, h1/h2 staged in LDS.
__global__ __launch_bounds__(512) void k_head(
    const unsigned* __restrict__ gu, const float* __restrict__ W1,
    const float* __restrict__ b1, const float* __restrict__ W2,
    const float* __restrict__ b2, const float* __restrict__ W3,
    const float* __restrict__ b3, float* __restrict__ out)
{
    __shared__ float gs[4][H_DIM];
    __shared__ float h1s[4][1024];
    __shared__ float h2s[4][512];
    int b0 = blockIdx.x * 4, t = threadIdx.x;
    if (t < 128) gs[t >> 5][t & 31] = fdec(gu[b0 * H_DIM + t]);
    __syncthreads();
    #pragma unroll
    for (int jj = 0; jj < 2; ++jj) {        // h1: 1024 cols, 4 graphs
        int j = jj * 512 + t;
        float a0 = b1[j], a1 = a0, a2 = a0, a3 = a0;
        #pragma unroll
        for (int k = 0; k < H_DIM; ++k) {
            float w = W1[k * 1024 + j];
            a0 = fmaf(gs[0][k], w, a0);
            a1 = fmaf(gs[1][k], w, a1);
            a2 = fmaf(gs[2][k], w, a2);
            a3 = fmaf(gs[3][k], w, a3);
        }
        h1s[0][j] = fmaxf(a0, 0.f);
        h1s[1][j] = fmaxf(a1, 0.f);
        h1s[2][j] = fmaxf(a2, 0.f);
        h1s[3][j] = fmaxf(a3, 0.f);
    }
    __syncthreads();
    {                                        // h2: 512 cols, 4 graphs
        float bb = b2[t];
        float a0 = bb, a1 = bb, a2 = bb, a3 = bb;
        for (int k = 0; k < 1024; ++k) {
            float w = W2[(size_t)k * 512 + t];
            a0 = fmaf(h1s[0][k], w, a0);
            a1 = fmaf(h1s[1][k], w, a1);
            a2 = fmaf(h1s[2][k], w, a2);
            a3 = fmaf(h1s[3][k], w, a3);
        }
        h2s[0][t] = fmaxf(a0, 0.f);
        h2s[1][t] = fmaxf(a1, 0.f);
        h2s[2][t] = fmaxf(a2, 0.f);
        h2s[3][t] = fmaxf(a3, 0.f);
    }
    __syncthreads();
    {                                        // out: 16 (g,c) pairs x 32 lanes
        int pair = t >> 5, lane = t & 31;
        int g = pair >> 2, c = pair & 3;
        float a = 0.f;
        for (int k = lane; k < 512; k += 32)
            a = fmaf(h2s[g][k], W3[k * 4 + c], a);
        a += __shfl_xor(a, 16); a += __shfl_xor(a, 8);
        a += __shfl_xor(a, 4);  a += __shfl_xor(a, 2); a += __shfl_xor(a, 1);
        if (lane == 0) out[(b0 + g) * 4 + c] = a + b3[c];
    }
}

extern "C" void kernel_launch(void* const* d_in, const int* in_sizes, int n_in,
                              void* d_out, int out_size, void* d_ws, size_t ws_size,
                              hipStream_t stream)
{
    const float* x     = (const float*)d_in[0];
    const int*   ei    = (const int*)d_in[1];
    const int*   batch = (const int*)d_in[2];
    const float* Wl    = (const float*)d_in[3];
    const float* Wr    = (const float*)d_in[4];
    const float* att   = (const float*)d_in[5];
    const float* bias  = (const float*)d_in[6];
    const float* W1    = (const float*)d_in[7];
    const float* b1    = (const float*)d_in[8];
    const float* W2    = (const float*)d_in[9];
    const float* b2    = (const float*)d_in[10];
    const float* W3    = (const float*)d_in[11];
    const float* b3    = (const float*)d_in[12];
    float* out = (float*)d_out;

    // workspace layout (~42 MB)
    float*    xl     = (float*)d_ws;                               // 3.2M f
    float*    xr     = xl + (size_t)N_NODES * H_DIM;               // 3.2M f
    unsigned* binbuf = (unsigned*)(xr + (size_t)N_NODES * H_DIM);  // 1000*4096
    int*      bcnt   = (int*)(binbuf + (size_t)N_FBIN * BIN_CAP);  // 16384 [memset]
    unsigned* gu     = (unsigned*)(bcnt + N_FBIN * CPAD);          // 8192  [memset]

    hipMemsetAsync(bcnt, 0, (size_t)(N_FBIN * CPAD + B_GR * H_DIM) * sizeof(int), stream);

    k_fused<<<PART_NBLK + LIN_BLK, 1024, 0, stream>>>(
        ei, bcnt, binbuf, x, Wl, Wr, xl, xr);
    k_aggregate<<<N_FBIN, 512, 0, stream>>>(binbuf, bcnt, xl, xr, att, bias, batch, gu);
    k_head<<<B_GR / 4, 512, 0, stream>>>(gu, W1, b1, W2, b2, W3, b3, out);
}

// Round 13
// 175.938 us; speedup vs baseline: 4.0570x; 1.1560x over previous
//
#include <hip/hip_runtime.h>

#define N_NODES 100000
#define N_EDGES 3200000
#define F_IN    128
#define H_DIM   32
#define B_GR    256
#define NEG     0.2f

#define FBIN_SZ  100
#define N_FBIN   (N_NODES / FBIN_SZ)        // 1000
#define BIN_CAP  4096                        // mean 3200, +15.8 sigma
#define CPAD     16                          // bcnt 64B padding
#define PART_T   1024
#define EPB_R    4                           // int4 rounds per thread
#define EPB_G    (PART_T * EPB_R)            // 4096 int4 groups = 16384 edges/block
#define PART_NBLK ((N_EDGES / 4 + EPB_G - 1) / EPB_G)   // 196
#define LIN_BLK  ((N_NODES + 63) / 64)       // 1563 (64 nodes/block)

// ---- monotonic float<->uint encoding for atomicMax on floats ----
__device__ __forceinline__ unsigned fenc(float f) {
    unsigned u = __float_as_uint(f);
    return (u & 0x80000000u) ? ~u : (u | 0x80000000u);
}
__device__ __forceinline__ float fdec(unsigned u) {
    return (u & 0x80000000u) ? __uint_as_float(u & 0x7FFFFFFFu)
                             : __uint_as_float(~u);
}

// K1: fat kernel. Blocks [0, PART_NBLK): two-pass direct-write edge binning
// (16384 edges/block in registers; pass1 LDS count, 1 global atomic per
// touched bin, pass2 LDS-cursor + direct global write -> ~full-line runs).
// Blocks [PART_NBLK, +LIN_BLK): xl = x@Wl, xr = x@Wr as 4 x 256-thread
// quarters sharing W tiles. Independent -> co-scheduled in one dispatch.
__global__ __launch_bounds__(1024) void k_fused(
    const int* __restrict__ ei, int* __restrict__ bcnt, unsigned* __restrict__ binbuf,
    const float* __restrict__ x, const float* __restrict__ Wl,
    const float* __restrict__ Wr, float* __restrict__ xl, float* __restrict__ xr)
{
    __shared__ __align__(16) float smem[16384];   // 64 KB union
    int t = threadIdx.x;

    if (blockIdx.x < PART_NBLK) {
        // ---------------- edge binning (two-pass, register-held) ----------------
        int* lcnt = (int*)smem;           // 1024 ints (1000 used)
        int* cur  = lcnt + 1024;          // 1024 ints
        lcnt[t] = 0;
        __syncthreads();

        int g0 = blockIdx.x * EPB_G;
        int4 s4[EPB_R], d4[EPB_R];
        int bb_[EPB_R][4];
        bool val[EPB_R];
        #pragma unroll
        for (int r = 0; r < EPB_R; ++r) {
            int i = g0 + r * PART_T + t;
            val[r] = i < N_EDGES / 4;
            if (val[r]) {
                s4[r] = ((const int4*)ei)[i];
                d4[r] = ((const int4*)(ei + N_EDGES))[i];
                bb_[r][0] = d4[r].x / FBIN_SZ;
                bb_[r][1] = d4[r].y / FBIN_SZ;
                bb_[r][2] = d4[r].z / FBIN_SZ;
                bb_[r][3] = d4[r].w / FBIN_SZ;
                atomicAdd(&lcnt[bb_[r][0]], 1);
                atomicAdd(&lcnt[bb_[r][1]], 1);
                atomicAdd(&lcnt[bb_[r][2]], 1);
                atomicAdd(&lcnt[bb_[r][3]], 1);
            }
        }
        __syncthreads();
        if (t < N_FBIN) {
            int c = lcnt[t];
            if (c > 0) cur[t] = atomicAdd(&bcnt[t * CPAD], c);
        }
        __syncthreads();
        #pragma unroll
        for (int r = 0; r < EPB_R; ++r) {
            if (val[r]) {
                int b, p;
                b = bb_[r][0]; p = atomicAdd(&cur[b], 1);
                binbuf[(size_t)b * BIN_CAP + p] = ((unsigned)(d4[r].x - b * FBIN_SZ) << 17) | (unsigned)s4[r].x;
                b = bb_[r][1]; p = atomicAdd(&cur[b], 1);
                binbuf[(size_t)b * BIN_CAP + p] = ((unsigned)(d4[r].y - b * FBIN_SZ) << 17) | (unsigned)s4[r].y;
                b = bb_[r][2]; p = atomicAdd(&cur[b], 1);
                binbuf[(size_t)b * BIN_CAP + p] = ((unsigned)(d4[r].z - b * FBIN_SZ) << 17) | (unsigned)s4[r].z;
                b = bb_[r][3]; p = atomicAdd(&cur[b], 1);
                binbuf[(size_t)b * BIN_CAP + p] = ((unsigned)(d4[r].w - b * FBIN_SZ) << 17) | (unsigned)s4[r].w;
            }
        }
    } else {
        // ---------------- linear: xl/xr ----------------
        float* Wls = smem;            // 4096
        float* Wrs = smem + 4096;     // 4096
        float* xsb = smem + 8192;     // 4 x 2048
        int blk = blockIdx.x - PART_NBLK;
        for (int i = t; i < F_IN * H_DIM; i += 1024) { Wls[i] = Wl[i]; Wrs[i] = Wr[i]; }
        int q = t >> 8, tq = t & 255;
        size_t base = (size_t)blk * 64 + q * 16;
        bool act = base < N_NODES;     // quarters are 16-aligned; all-or-nothing
        float* xs = xsb + q * 2048;
        if (act) {
            const float4* xg = (const float4*)(x + base * F_IN);
            float4* xs4 = (float4*)xs;
            xs4[tq] = xg[tq];
            xs4[tq + 256] = xg[tq + 256];
        }
        __syncthreads();
        if (act) {
            int nl = tq >> 5, h = tq & 31;
            float al0 = 0.f, ar0 = 0.f, al1 = 0.f, ar1 = 0.f;
            const float4* xa4 = (const float4*)(xs + nl * F_IN);
            const float4* xb4 = (const float4*)(xs + (nl + 8) * F_IN);
            #pragma unroll 8
            for (int f4 = 0; f4 < 32; ++f4) {
                float4 xa = xa4[f4], xb = xb4[f4];
                int fb = f4 * 4;
                float w;
                w = Wls[(fb + 0) * 32 + h]; al0 = fmaf(xa.x, w, al0); al1 = fmaf(xb.x, w, al1);
                w = Wls[(fb + 1) * 32 + h]; al0 = fmaf(xa.y, w, al0); al1 = fmaf(xb.y, w, al1);
                w = Wls[(fb + 2) * 32 + h]; al0 = fmaf(xa.z, w, al0); al1 = fmaf(xb.z, w, al1);
                w = Wls[(fb + 3) * 32 + h]; al0 = fmaf(xa.w, w, al0); al1 = fmaf(xb.w, w, al1);
                w = Wrs[(fb + 0) * 32 + h]; ar0 = fmaf(xa.x, w, ar0); ar1 = fmaf(xb.x, w, ar1);
                w = Wrs[(fb + 1) * 32 + h]; ar0 = fmaf(xa.y, w, ar0); ar1 = fmaf(xb.y, w, ar1);
                w = Wrs[(fb + 2) * 32 + h]; ar0 = fmaf(xa.z, w, ar0); ar1 = fmaf(xb.z, w, ar1);
                w = Wrs[(fb + 3) * 32 + h]; ar0 = fmaf(xa.w, w, ar0); ar1 = fmaf(xb.w, w, ar1);
            }
            size_t n0 = base + nl, n1 = base + nl + 8;
            xl[n0 * 32 + h] = al0; xr[n0 * 32 + h] = ar0;
            xl[n1 * 32 + h] = al1; xr[n1 * 32 + h] = ar1;
        }
    }
}

// K2: per-bin in-LDS CSR build + fused score/softmax/aggregate/pool (r10).
__global__ __launch_bounds__(512) void k_aggregate(
    const unsigned* __restrict__ binbuf, const int* __restrict__ bcnt,
    const float* __restrict__ xl, const float* __restrict__ xr,
    const float* __restrict__ att, const float* __restrict__ bias,
    const int* __restrict__ batch, unsigned* __restrict__ gu)
{
    __shared__ unsigned eL[BIN_CAP];      // 16 KB sorted edge list
    __shared__ int cnt[128];
    __shared__ int sc[128];
    __shared__ int cur[128];
    __shared__ unsigned lmax[64];         // bin spans <= 2 graphs (100 < 390)
    int t = threadIdx.x;
    int bin = blockIdx.x;
    int n_e = bcnt[bin * CPAD];
    const unsigned* bb = binbuf + (size_t)bin * BIN_CAP;

    if (t < 128) cnt[t] = 0;
    if (t < 64) lmax[t] = 0u;             // encodes -inf
    __syncthreads();
    for (int i = t; i < n_e; i += 512)
        atomicAdd(&cnt[bb[i] >> 17], 1);
    __syncthreads();
    if (t < 128) sc[t] = cnt[t];
    __syncthreads();
    for (int off = 1; off < 128; off <<= 1) {
        int v = 0;
        if (t < 128 && t >= off) v = sc[t - off];
        __syncthreads();
        if (t < 128) sc[t] += v;
        __syncthreads();
    }
    if (t < 128) cur[t] = sc[t] - cnt[t];
    __syncthreads();
    for (int i = t; i < n_e; i += 512) {
        unsigned u = bb[i];
        int p = atomicAdd(&cur[u >> 17], 1);
        eL[p] = u;
    }
    __syncthreads();

    int lane = t & 63;
    int wv = t >> 6;
    int half = lane >> 5;
    int gid = (lane >> 4) & 1;
    int hp = lane & 15;
    const float2 a2 = ((const float2*)att)[hp];
    const float2 b2 = ((const float2*)bias)[hp];
    int lg0 = batch[bin * FBIN_SZ];

    for (int nl = wv * 2 + half; nl < FBIN_SZ; nl += 16) {
        int n = bin * FBIN_SZ + nl;
        int e0 = (nl > 0) ? sc[nl - 1] : 0;
        int e1 = sc[nl];
        const float2 xr2 = ((const float2*)(xr + (size_t)n * H_DIM))[hp];
        const float2 xl2 = ((const float2*)(xl + (size_t)n * H_DIM))[hp];

        float vx = xl2.x + xr2.x; vx = fmaxf(vx, vx * NEG);
        float vy = xl2.y + xr2.y; vy = fmaxf(vy, vy * NEG);
        float pr = vx * a2.x; pr = fmaf(vy, a2.y, pr);
        pr += __shfl_xor(pr, 1); pr += __shfl_xor(pr, 2);
        pr += __shfl_xor(pr, 4); pr += __shfl_xor(pr, 8);
        float z = 0.f; float2 acc = make_float2(0.f, 0.f);
        if (gid == 0) {
            float p = __expf(fminf(pr, 70.f));
            z = p; acc.x = p * xl2.x; acc.y = p * xl2.y;
        }

        int j = e0 + gid;
        for (; j + 2 < e1; j += 4) {
            unsigned uA = eL[j], uB = eL[j + 2];
            int sA = (int)(uA & 0x1FFFFu), sB = (int)(uB & 0x1FFFFu);
            float2 xA = ((const float2*)(xl + (size_t)sA * H_DIM))[hp];
            float2 xB = ((const float2*)(xl + (size_t)sB * H_DIM))[hp];
            float ax = xA.x + xr2.x; ax = fmaxf(ax, ax * NEG);
            float ay = xA.y + xr2.y; ay = fmaxf(ay, ay * NEG);
            float bx = xB.x + xr2.x; bx = fmaxf(bx, bx * NEG);
            float by = xB.y + xr2.y; by = fmaxf(by, by * NEG);
            float pA = ax * a2.x; pA = fmaf(ay, a2.y, pA);
            float pB = bx * a2.x; pB = fmaf(by, a2.y, pB);
            pA += __shfl_xor(pA, 1); pB += __shfl_xor(pB, 1);
            pA += __shfl_xor(pA, 2); pB += __shfl_xor(pB, 2);
            pA += __shfl_xor(pA, 4); pB += __shfl_xor(pB, 4);
            pA += __shfl_xor(pA, 8); pB += __shfl_xor(pB, 8);
            float eA = __expf(fminf(pA, 70.f));
            float eB = __expf(fminf(pB, 70.f));
            z += eA + eB;
            acc.x = fmaf(eA, xA.x, acc.x); acc.y = fmaf(eA, xA.y, acc.y);
            acc.x = fmaf(eB, xB.x, acc.x); acc.y = fmaf(eB, xB.y, acc.y);
        }
        for (; j < e1; j += 2) {
            unsigned u = eL[j];
            int s = (int)(u & 0x1FFFFu);
            float2 xs2 = ((const float2*)(xl + (size_t)s * H_DIM))[hp];
            float ex = xs2.x + xr2.x; ex = fmaxf(ex, ex * NEG);
            float ey = xs2.y + xr2.y; ey = fmaxf(ey, ey * NEG);
            float pp = ex * a2.x; pp = fmaf(ey, a2.y, pp);
            pp += __shfl_xor(pp, 1); pp += __shfl_xor(pp, 2);
            pp += __shfl_xor(pp, 4); pp += __shfl_xor(pp, 8);
            float p = __expf(fminf(pp, 70.f));
            z += p;
            acc.x = fmaf(p, xs2.x, acc.x);
            acc.y = fmaf(p, xs2.y, acc.y);
        }

        z += __shfl_xor(z, 16);
        acc.x += __shfl_xor(acc.x, 16);
        acc.y += __shfl_xor(acc.y, 16);

        if (gid == 0) {
            float inv = 1.f / z;
            float ox = fmaf(acc.x, inv, b2.x);
            float oy = fmaf(acc.y, inv, b2.y);
            int gi = batch[n] - lg0;
            atomicMax(&lmax[gi * 32 + hp * 2 + 0], fenc(ox));
            atomicMax(&lmax[gi * 32 + hp * 2 + 1], fenc(oy));
        }
    }
    __syncthreads();
    if (t < 64) {
        int g = lg0 + (t >> 5);
        int glast = batch[bin * FBIN_SZ + FBIN_SZ - 1];
        if (g <= glast) atomicMax(&gu[g * H_DIM + (t & 31)], lmax[t]);
    }
}

// K3: MLP head, one graph per block (256 blocks), h1/h2 in LDS, 4-way
// K-slice ILP in the W2 stage.
__global__ __launch_bounds__(512) void k_head(
    const unsigned* __restrict__ gu, const float* __restrict__ W1,
    const float* __restrict__ b1, const float* __restrict__ W2,
    const float* __restrict__ b2, const float* __restrict__ W3,
    const float* __restrict__ b3, float* __restrict__ out)
{
    __shared__ float gs[H_DIM];
    __shared__ float h1s[1024];
    __shared__ float h2s[512];
    int b = blockIdx.x, t = threadIdx.x;
    if (t < H_DIM) gs[t] = fdec(gu[b * H_DIM + t]);
    __syncthreads();
    #pragma unroll
    for (int jj = 0; jj < 2; ++jj) {        // h1: 1024 cols
        int j = jj * 512 + t;
        float a = b1[j];
        #pragma unroll
        for (int k = 0; k < H_DIM; ++k) a = fmaf(gs[k], W1[k * 1024 + j], a);
        h1s[j] = fmaxf(a, 0.f);
    }
    __syncthreads();
    {                                        // h2: 512 cols, 4 K-slices ILP
        float a0 = 0.f, a1 = 0.f, a2 = 0.f, a3 = 0.f;
        #pragma unroll 4
        for (int k = 0; k < 256; ++k) {
            a0 = fmaf(h1s[k      ], W2[(size_t)(k      ) * 512 + t], a0);
            a1 = fmaf(h1s[k + 256], W2[(size_t)(k + 256) * 512 + t], a1);
            a2 = fmaf(h1s[k + 512], W2[(size_t)(k + 512) * 512 + t], a2);
            a3 = fmaf(h1s[k + 768], W2[(size_t)(k + 768) * 512 + t], a3);
        }
        h2s[t] = fmaxf((a0 + a1) + (a2 + a3) + b2[t], 0.f);
    }
    __syncthreads();
    if (t < 256) {                           // out: 4 classes x 64 lanes
        int c = t >> 6, lane = t & 63;
        float a = 0.f;
        #pragma unroll
        for (int k = lane; k < 512; k += 64)
            a = fmaf(h2s[k], W3[k * 4 + c], a);
        for (int off = 32; off; off >>= 1) a += __shfl_down(a, off);
        if (lane == 0) out[b * 4 + c] = a + b3[c];
    }
}

extern "C" void kernel_launch(void* const* d_in, const int* in_sizes, int n_in,
                              void* d_out, int out_size, void* d_ws, size_t ws_size,
                              hipStream_t stream)
{
    const float* x     = (const float*)d_in[0];
    const int*   ei    = (const int*)d_in[1];
    const int*   batch = (const int*)d_in[2];
    const float* Wl    = (const float*)d_in[3];
    const float* Wr    = (const float*)d_in[4];
    const float* att   = (const float*)d_in[5];
    const float* bias  = (const float*)d_in[6];
    const float* W1    = (const float*)d_in[7];
    const float* b1    = (const float*)d_in[8];
    const float* W2    = (const float*)d_in[9];
    const float* b2    = (const float*)d_in[10];
    const float* W3    = (const float*)d_in[11];
    const float* b3    = (const float*)d_in[12];
    float* out = (float*)d_out;

    // workspace layout (~42 MB)
    float*    xl     = (float*)d_ws;                               // 3.2M f
    float*    xr     = xl + (size_t)N_NODES * H_DIM;               // 3.2M f
    unsigned* binbuf = (unsigned*)(xr + (size_t)N_NODES * H_DIM);  // 1000*4096
    int*      bcnt   = (int*)(binbuf + (size_t)N_FBIN * BIN_CAP);  // 16384 [memset]
    unsigned* gu     = (unsigned*)(bcnt + N_FBIN * CPAD);          // 8192  [memset]

    hipMemsetAsync(bcnt, 0, (size_t)(N_FBIN * CPAD + B_GR * H_DIM) * sizeof(int), stream);

    k_fused<<<PART_NBLK + LIN_BLK, 1024, 0, stream>>>(
        ei, bcnt, binbuf, x, Wl, Wr, xl, xr);
    k_aggregate<<<N_FBIN, 512, 0, stream>>>(binbuf, bcnt, xl, xr, att, bias, batch, gu);
    k_head<<<B_GR / 4 * 4, 512, 0, stream>>>(gu, W1, b1, W2, b2, W3, b3, out);
}

// Round 14
// 170.401 us; speedup vs baseline: 4.1888x; 1.0325x over previous
//
#include <hip/hip_runtime.h>

#define N_NODES 100000
#define N_EDGES 3200000
#define F_IN    128
#define H_DIM   32
#define B_GR    256
#define NEG     0.2f

#define FBIN_SZ  100
#define N_FBIN   (N_NODES / FBIN_SZ)        // 1000
#define BIN_CAP  4096                        // mean 3200, +15.8 sigma
#define CPAD     16                          // bcnt 64B padding
#define PART_T   1024
#define EPB_R    8                           // int4 rounds per thread (re-read, no reg cache)
#define EPB_G    (PART_T * EPB_R)            // 8192 int4 groups = 32768 edges/block
#define PART_NBLK ((N_EDGES / 4 + EPB_G - 1) / EPB_G)   // 98
#define LIN_BLK  ((N_NODES + 63) / 64)       // 1563 (64 nodes/block)

// ---- monotonic float<->uint encoding for atomicMax on floats ----
__device__ __forceinline__ unsigned fenc(float f) {
    unsigned u = __float_as_uint(f);
    return (u & 0x80000000u) ? ~u : (u | 0x80000000u);
}
__device__ __forceinline__ float fdec(unsigned u) {
    return (u & 0x80000000u) ? __uint_as_float(u & 0x7FFFFFFFu)
                             : __uint_as_float(~u);
}

// K1: fat kernel. Blocks [0, PART_NBLK): two-pass edge binning, 32768
// edges/block; pass1 reads dst only -> LDS hist; one global atomic per
// touched bin; pass2 re-reads ei (L2-hot) and direct-writes ~full-line runs.
// Blocks [PART_NBLK, +LIN_BLK): xl = x@Wl, xr = x@Wr as 4 x 256-thread
// quarters sharing W tiles. Independent -> co-scheduled in one dispatch.
__global__ __launch_bounds__(1024) void k_fused(
    const int* __restrict__ ei, int* __restrict__ bcnt, unsigned* __restrict__ binbuf,
    const float* __restrict__ x, const float* __restrict__ Wl,
    const float* __restrict__ Wr, float* __restrict__ xl, float* __restrict__ xr)
{
    __shared__ __align__(16) float smem[16384];   // 64 KB union
    int t = threadIdx.x;

    if (blockIdx.x < PART_NBLK) {
        // ---------------- edge binning (two-pass, re-read) ----------------
        int* lcnt = (int*)smem;           // 1024 ints (1000 used)
        int* cur  = lcnt + 1024;          // 1024 ints
        lcnt[t] = 0;
        __syncthreads();
        int g0 = blockIdx.x * EPB_G;
        const int4* dsrc = (const int4*)(ei + N_EDGES);
        const int4* ssrc = (const int4*)ei;
        #pragma unroll
        for (int r = 0; r < EPB_R; ++r) {
            int i = g0 + r * PART_T + t;
            if (i < N_EDGES / 4) {
                int4 d = dsrc[i];
                atomicAdd(&lcnt[d.x / FBIN_SZ], 1);
                atomicAdd(&lcnt[d.y / FBIN_SZ], 1);
                atomicAdd(&lcnt[d.z / FBIN_SZ], 1);
                atomicAdd(&lcnt[d.w / FBIN_SZ], 1);
            }
        }
        __syncthreads();
        if (t < N_FBIN) {
            int c = lcnt[t];
            if (c > 0) cur[t] = atomicAdd(&bcnt[t * CPAD], c);
        }
        __syncthreads();
        #pragma unroll
        for (int r = 0; r < EPB_R; ++r) {
            int i = g0 + r * PART_T + t;
            if (i < N_EDGES / 4) {
                int4 s = ssrc[i];
                int4 d = dsrc[i];
                int b, p;
                b = d.x / FBIN_SZ; p = atomicAdd(&cur[b], 1);
                binbuf[(size_t)b * BIN_CAP + p] = ((unsigned)(d.x - b * FBIN_SZ) << 17) | (unsigned)s.x;
                b = d.y / FBIN_SZ; p = atomicAdd(&cur[b], 1);
                binbuf[(size_t)b * BIN_CAP + p] = ((unsigned)(d.y - b * FBIN_SZ) << 17) | (unsigned)s.y;
                b = d.z / FBIN_SZ; p = atomicAdd(&cur[b], 1);
                binbuf[(size_t)b * BIN_CAP + p] = ((unsigned)(d.z - b * FBIN_SZ) << 17) | (unsigned)s.z;
                b = d.w / FBIN_SZ; p = atomicAdd(&cur[b], 1);
                binbuf[(size_t)b * BIN_CAP + p] = ((unsigned)(d.w - b * FBIN_SZ) << 17) | (unsigned)s.w;
            }
        }
    } else {
        // ---------------- linear: xl/xr ----------------
        float* Wls = smem;            // 4096
        float* Wrs = smem + 4096;     // 4096
        float* xsb = smem + 8192;     // 4 x 2048
        int blk = blockIdx.x - PART_NBLK;
        for (int i = t; i < F_IN * H_DIM; i += 1024) { Wls[i] = Wl[i]; Wrs[i] = Wr[i]; }
        int q = t >> 8, tq = t & 255;
        size_t base = (size_t)blk * 64 + q * 16;
        bool act = base < N_NODES;     // quarters are 16-aligned; all-or-nothing
        float* xs = xsb + q * 2048;
        if (act) {
            const float4* xg = (const float4*)(x + base * F_IN);
            float4* xs4 = (float4*)xs;
            xs4[tq] = xg[tq];
            xs4[tq + 256] = xg[tq + 256];
        }
        __syncthreads();
        if (act) {
            int nl = tq >> 5, h = tq & 31;
            float al0 = 0.f, ar0 = 0.f, al1 = 0.f, ar1 = 0.f;
            const float4* xa4 = (const float4*)(xs + nl * F_IN);
            const float4* xb4 = (const float4*)(xs + (nl + 8) * F_IN);
            #pragma unroll 8
            for (int f4 = 0; f4 < 32; ++f4) {
                float4 xa = xa4[f4], xb = xb4[f4];
                int fb = f4 * 4;
                float w;
                w = Wls[(fb + 0) * 32 + h]; al0 = fmaf(xa.x, w, al0); al1 = fmaf(xb.x, w, al1);
                w = Wls[(fb + 1) * 32 + h]; al0 = fmaf(xa.y, w, al0); al1 = fmaf(xb.y, w, al1);
                w = Wls[(fb + 2) * 32 + h]; al0 = fmaf(xa.z, w, al0); al1 = fmaf(xb.z, w, al1);
                w = Wls[(fb + 3) * 32 + h]; al0 = fmaf(xa.w, w, al0); al1 = fmaf(xb.w, w, al1);
                w = Wrs[(fb + 0) * 32 + h]; ar0 = fmaf(xa.x, w, ar0); ar1 = fmaf(xb.x, w, ar1);
                w = Wrs[(fb + 1) * 32 + h]; ar0 = fmaf(xa.y, w, ar0); ar1 = fmaf(xb.y, w, ar1);
                w = Wrs[(fb + 2) * 32 + h]; ar0 = fmaf(xa.z, w, ar0); ar1 = fmaf(xb.z, w, ar1);
                w = Wrs[(fb + 3) * 32 + h]; ar0 = fmaf(xa.w, w, ar0); ar1 = fmaf(xb.w, w, ar1);
            }
            size_t n0 = base + nl, n1 = base + nl + 8;
            xl[n0 * 32 + h] = al0; xr[n0 * 32 + h] = ar0;
            xl[n1 * 32 + h] = al1; xr[n1 * 32 + h] = ar1;
        }
    }
}

// K2: per-bin in-LDS CSR build + fused score/softmax/aggregate/pool.
// Phase 2: half-wave = node, two 16-lane streams, lane = h-pair (float2),
// 4-deep unroll per stream (8 edges in flight per half-wave).
__global__ __launch_bounds__(512) void k_aggregate(
    const unsigned* __restrict__ binbuf, const int* __restrict__ bcnt,
    const float* __restrict__ xl, const float* __restrict__ xr,
    const float* __restrict__ att, const float* __restrict__ bias,
    const int* __restrict__ batch, unsigned* __restrict__ gu)
{
    __shared__ unsigned eL[BIN_CAP];      // 16 KB sorted edge list
    __shared__ int cnt[128];
    __shared__ int sc[128];
    __shared__ int cur[128];
    __shared__ unsigned lmax[64];         // bin spans <= 2 graphs (100 < 390)
    int t = threadIdx.x;
    int bin = blockIdx.x;
    int n_e = bcnt[bin * CPAD];
    const unsigned* bb = binbuf + (size_t)bin * BIN_CAP;

    if (t < 128) cnt[t] = 0;
    if (t < 64) lmax[t] = 0u;             // encodes -inf
    __syncthreads();
    for (int i = t; i < n_e; i += 512)
        atomicAdd(&cnt[bb[i] >> 17], 1);
    __syncthreads();
    if (t < 128) sc[t] = cnt[t];
    __syncthreads();
    for (int off = 1; off < 128; off <<= 1) {
        int v = 0;
        if (t < 128 && t >= off) v = sc[t - off];
        __syncthreads();
        if (t < 128) sc[t] += v;
        __syncthreads();
    }
    if (t < 128) cur[t] = sc[t] - cnt[t];
    __syncthreads();
    for (int i = t; i < n_e; i += 512) {
        unsigned u = bb[i];
        int p = atomicAdd(&cur[u >> 17], 1);
        eL[p] = u;
    }
    __syncthreads();

    int lane = t & 63;
    int wv = t >> 6;
    int half = lane >> 5;
    int gid = (lane >> 4) & 1;
    int hp = lane & 15;
    const float2 a2 = ((const float2*)att)[hp];
    const float2 b2 = ((const float2*)bias)[hp];
    int lg0 = batch[bin * FBIN_SZ];

    for (int nl = wv * 2 + half; nl < FBIN_SZ; nl += 16) {
        int n = bin * FBIN_SZ + nl;
        int e0 = (nl > 0) ? sc[nl - 1] : 0;
        int e1 = sc[nl];
        const float2 xr2 = ((const float2*)(xr + (size_t)n * H_DIM))[hp];
        const float2 xl2 = ((const float2*)(xl + (size_t)n * H_DIM))[hp];

        float vx = xl2.x + xr2.x; vx = fmaxf(vx, vx * NEG);
        float vy = xl2.y + xr2.y; vy = fmaxf(vy, vy * NEG);
        float pr = vx * a2.x; pr = fmaf(vy, a2.y, pr);
        pr += __shfl_xor(pr, 1); pr += __shfl_xor(pr, 2);
        pr += __shfl_xor(pr, 4); pr += __shfl_xor(pr, 8);
        float z = 0.f; float2 acc = make_float2(0.f, 0.f);
        if (gid == 0) {
            float p = __expf(fminf(pr, 70.f));
            z = p; acc.x = p * xl2.x; acc.y = p * xl2.y;
        }

        int j = e0 + gid;
        for (; j + 6 < e1; j += 8) {          // 4-deep unroll per stream
            unsigned u0 = eL[j], u1 = eL[j + 2], u2 = eL[j + 4], u3 = eL[j + 6];
            int s0 = (int)(u0 & 0x1FFFFu), s1 = (int)(u1 & 0x1FFFFu);
            int s2 = (int)(u2 & 0x1FFFFu), s3 = (int)(u3 & 0x1FFFFu);
            float2 x0 = ((const float2*)(xl + (size_t)s0 * H_DIM))[hp];
            float2 x1 = ((const float2*)(xl + (size_t)s1 * H_DIM))[hp];
            float2 x2 = ((const float2*)(xl + (size_t)s2 * H_DIM))[hp];
            float2 x3 = ((const float2*)(xl + (size_t)s3 * H_DIM))[hp];
            float p0, p1, p2, p3;
            {
                float ax = x0.x + xr2.x; ax = fmaxf(ax, ax * NEG);
                float ay = x0.y + xr2.y; ay = fmaxf(ay, ay * NEG);
                p0 = ax * a2.x; p0 = fmaf(ay, a2.y, p0);
            }
            {
                float ax = x1.x + xr2.x; ax = fmaxf(ax, ax * NEG);
                float ay = x1.y + xr2.y; ay = fmaxf(ay, ay * NEG);
                p1 = ax * a2.x; p1 = fmaf(ay, a2.y, p1);
            }
            {
                float ax = x2.x + xr2.x; ax = fmaxf(ax, ax * NEG);
                float ay = x2.y + xr2.y; ay = fmaxf(ay, ay * NEG);
                p2 = ax * a2.x; p2 = fmaf(ay, a2.y, p2);
            }
            {
                float ax = x3.x + xr2.x; ax = fmaxf(ax, ax * NEG);
                float ay = x3.y + xr2.y; ay = fmaxf(ay, ay * NEG);
                p3 = ax * a2.x; p3 = fmaf(ay, a2.y, p3);
            }
            p0 += __shfl_xor(p0, 1); p1 += __shfl_xor(p1, 1);
            p2 += __shfl_xor(p2, 1); p3 += __shfl_xor(p3, 1);
            p0 += __shfl_xor(p0, 2); p1 += __shfl_xor(p1, 2);
            p2 += __shfl_xor(p2, 2); p3 += __shfl_xor(p3, 2);
            p0 += __shfl_xor(p0, 4); p1 += __shfl_xor(p1, 4);
            p2 += __shfl_xor(p2, 4); p3 += __shfl_xor(p3, 4);
            p0 += __shfl_xor(p0, 8); p1 += __shfl_xor(p1, 8);
            p2 += __shfl_xor(p2, 8); p3 += __shfl_xor(p3, 8);
            float e0f = __expf(fminf(p0, 70.f));
            float e1f = __expf(fminf(p1, 70.f));
            float e2f = __expf(fminf(p2, 70.f));
            float e3f = __expf(fminf(p3, 70.f));
            z += (e0f + e1f) + (e2f + e3f);
            acc.x = fmaf(e0f, x0.x, acc.x); acc.y = fmaf(e0f, x0.y, acc.y);
            acc.x = fmaf(e1f, x1.x, acc.x); acc.y = fmaf(e1f, x1.y, acc.y);
            acc.x = fmaf(e2f, x2.x, acc.x); acc.y = fmaf(e2f, x2.y, acc.y);
            acc.x = fmaf(e3f, x3.x, acc.x); acc.y = fmaf(e3f, x3.y, acc.y);
        }
        for (; j < e1; j += 2) {
            unsigned u = eL[j];
            int s = (int)(u & 0x1FFFFu);
            float2 xs2 = ((const float2*)(xl + (size_t)s * H_DIM))[hp];
            float ex = xs2.x + xr2.x; ex = fmaxf(ex, ex * NEG);
            float ey = xs2.y + xr2.y; ey = fmaxf(ey, ey * NEG);
            float pp = ex * a2.x; pp = fmaf(ey, a2.y, pp);
            pp += __shfl_xor(pp, 1); pp += __shfl_xor(pp, 2);
            pp += __shfl_xor(pp, 4); pp += __shfl_xor(pp, 8);
            float p = __expf(fminf(pp, 70.f));
            z += p;
            acc.x = fmaf(p, xs2.x, acc.x);
            acc.y = fmaf(p, xs2.y, acc.y);
        }

        z += __shfl_xor(z, 16);
        acc.x += __shfl_xor(acc.x, 16);
        acc.y += __shfl_xor(acc.y, 16);

        if (gid == 0) {
            float inv = 1.f / z;
            float ox = fmaf(acc.x, inv, b2.x);
            float oy = fmaf(acc.y, inv, b2.y);
            int gi = batch[n] - lg0;
            atomicMax(&lmax[gi * 32 + hp * 2 + 0], fenc(ox));
            atomicMax(&lmax[gi * 32 + hp * 2 + 1], fenc(oy));
        }
    }
    __syncthreads();
    if (t < 64) {
        int g = lg0 + (t >> 5);
        int glast = batch[bin * FBIN_SZ + FBIN_SZ - 1];
        if (g <= glast) atomicMax(&gu[g * H_DIM + (t & 31)], lmax[t]);
    }
}

// K3: MLP head, one graph per block (256 blocks), h1/h2 in LDS, 4-way
// K-slice ILP in the W2 stage.
__global__ __launch_bounds__(512) void k_head(
    const unsigned* __restrict__ gu, const float* __restrict__ W1,
    const float* __restrict__ b1, const float* __restrict__ W2,
    const float* __restrict__ b2, const float* __restrict__ W3,
    const float* __restrict__ b3, float* __restrict__ out)
{
    __shared__ float gs[H_DIM];
    __shared__ float h1s[1024];
    __shared__ float h2s[512];
    int b = blockIdx.x, t = threadIdx.x;
    if (t < H_DIM) gs[t] = fdec(gu[b * H_DIM + t]);
    __syncthreads();
    #pragma unroll
    for (int jj = 0; jj < 2; ++jj) {        // h1: 1024 cols
        int j = jj * 512 + t;
        float a = b1[j];
        #pragma unroll
        for (int k = 0; k < H_DIM; ++k) a = fmaf(gs[k], W1[k * 1024 + j], a);
        h1s[j] = fmaxf(a, 0.f);
    }
    __syncthreads();
    {                                        // h2: 512 cols, 4 K-slices ILP
        float a0 = 0.f, a1 = 0.f, a2 = 0.f, a3 = 0.f;
        #pragma unroll 4
        for (int k = 0; k < 256; ++k) {
            a0 = fmaf(h1s[k      ], W2[(size_t)(k      ) * 512 + t], a0);
            a1 = fmaf(h1s[k + 256], W2[(size_t)(k + 256) * 512 + t], a1);
            a2 = fmaf(h1s[k + 512], W2[(size_t)(k + 512) * 512 + t], a2);
            a3 = fmaf(h1s[k + 768], W2[(size_t)(k + 768) * 512 + t], a3);
        }
        h2s[t] = fmaxf((a0 + a1) + (a2 + a3) + b2[t], 0.f);
    }
    __syncthreads();
    if (t < 256) {                           // out: 4 classes x 64 lanes
        int c = t >> 6, lane = t & 63;
        float a = 0.f;
        #pragma unroll
        for (int k = lane; k < 512; k += 64)
            a = fmaf(h2s[k], W3[k * 4 + c], a);
        for (int off = 32; off; off >>= 1) a += __shfl_down(a, off);
        if (lane == 0) out[b * 4 + c] = a + b3[c];
    }
}

extern "C" void kernel_launch(void* const* d_in, const int* in_sizes, int n_in,
                              void* d_out, int out_size, void* d_ws, size_t ws_size,
                              hipStream_t stream)
{
    const float* x     = (const float*)d_in[0];
    const int*   ei    = (const int*)d_in[1];
    const int*   batch = (const int*)d_in[2];
    const float* Wl    = (const float*)d_in[3];
    const float* Wr    = (const float*)d_in[4];
    const float* att   = (const float*)d_in[5];
    const float* bias  = (const float*)d_in[6];
    const float* W1    = (const float*)d_in[7];
    const float* b1    = (const float*)d_in[8];
    const float* W2    = (const float*)d_in[9];
    const float* b2    = (const float*)d_in[10];
    const float* W3    = (const float*)d_in[11];
    const float* b3    = (const float*)d_in[12];
    float* out = (float*)d_out;

    // workspace layout (~42 MB)
    float*    xl     = (float*)d_ws;                               // 3.2M f
    float*    xr     = xl + (size_t)N_NODES * H_DIM;               // 3.2M f
    unsigned* binbuf = (unsigned*)(xr + (size_t)N_NODES * H_DIM);  // 1000*4096
    int*      bcnt   = (int*)(binbuf + (size_t)N_FBIN * BIN_CAP);  // 16384 [memset]
    unsigned* gu     = (unsigned*)(bcnt + N_FBIN * CPAD);          // 8192  [memset]

    hipMemsetAsync(bcnt, 0, (size_t)(N_FBIN * CPAD + B_GR * H_DIM) * sizeof(int), stream);

    k_fused<<<PART_NBLK + LIN_BLK, 1024, 0, stream>>>(
        ei, bcnt, binbuf, x, Wl, Wr, xl, xr);
    k_aggregate<<<N_FBIN, 512, 0, stream>>>(binbuf, bcnt, xl, xr, att, bias, batch, gu);
    k_head<<<B_GR, 512, 0, stream>>>(gu, W1, b1, W2, b2, W3, b3, out);
}